// Round 3
// baseline (561.555 us; speedup 1.0000x reference)
//
#include <hip/hip_runtime.h>
#include <math.h>

namespace {

constexpr int B_ = 4;
constexpr int C_ = 256;
constexpr int C4_ = 64;
constexpr int N_ = 4096;

typedef __attribute__((ext_vector_type(8))) short bf16x8;
typedef __attribute__((ext_vector_type(4))) float f32x4;

__device__ __forceinline__ unsigned short bf16_rne(float f) {
    unsigned u = __float_as_uint(f);
    u += 0x7fffu + ((u >> 16) & 1u);
    return (unsigned short)(u >> 16);
}

// Convert wq||wv -> wcomb bf16 [320,256], wt -> wtb bf16 [256,256].
__global__ __launch_bounds__(256) void cvt_kernel(
        const float* __restrict__ wq, const float* __restrict__ wv,
        const float* __restrict__ wt, unsigned short* __restrict__ wcomb,
        unsigned short* __restrict__ wtb) {
    const int i = (blockIdx.x * 256 + threadIdx.x) * 4;
    const float* src;
    unsigned short* dst;
    if (i < 16384) { src = wq + i; dst = wcomb + i; }
    else if (i < 81920) { src = wv + (i - 16384); dst = wcomb + i; }
    else { src = wt + (i - 81920); dst = wtb + (i - 81920); }
    const float4 f = *reinterpret_cast<const float4*>(src);
    ushort4 u;
    u.x = bf16_rne(f.x); u.y = bf16_rne(f.y);
    u.z = bf16_rne(f.z); u.w = bf16_rne(f.w);
    *reinterpret_cast<ushort4*>(dst) = u;
}

// MFMA projection: one 1024-thread block per 64-n tile; 16 waves = 4 n-strips
// x 4 o-quarters (5 ot each). x staged once per block.
__global__ __launch_bounds__(1024, 4) void proj_kernel(
        const float* __restrict__ x, const unsigned short* __restrict__ wcomb,
        const float* __restrict__ bv, unsigned short* __restrict__ qkT,
        unsigned short* __restrict__ v) {
    __shared__ unsigned short xs[2][64][40];
    const int b = blockIdx.y;
    const int n0 = blockIdx.x * 64;
    const int tid = threadIdx.x;
    const int wave = tid >> 6, lane = tid & 63;
    const int ws = wave & 3, oq = wave >> 2;
    const int quad = lane >> 4, l15 = lane & 15;
    const int ca = tid >> 6, na = tid & 63;
    const int cb = (tid + 1024) >> 6, nb2 = (tid + 1024) & 63;
    f32x4 acc[5];
#pragma unroll
    for (int ot = 0; ot < 5; ++ot) acc[ot] = (f32x4){0.f, 0.f, 0.f, 0.f};
    xs[0][na][ca] = bf16_rne(x[((size_t)b * C_ + ca) * N_ + n0 + na]);
    xs[0][nb2][cb] = bf16_rne(x[((size_t)b * C_ + cb) * N_ + n0 + nb2]);
    __syncthreads();
    for (int ch = 0; ch < 8; ++ch) {
        const int buf = ch & 1;
        float la = 0.f, lb = 0.f;
        if (ch < 7) {
            la = x[((size_t)b * C_ + (ch + 1) * 32 + ca) * N_ + n0 + na];
            lb = x[((size_t)b * C_ + (ch + 1) * 32 + cb) * N_ + n0 + nb2];
        }
        const bf16x8 a = *reinterpret_cast<const bf16x8*>(&xs[buf][ws * 16 + l15][quad * 8]);
#pragma unroll
        for (int ot = 0; ot < 5; ++ot) {
            const int gro = oq * 5 + ot;
            const bf16x8 wb = *reinterpret_cast<const bf16x8*>(
                wcomb + (size_t)(gro * 16 + l15) * C_ + ch * 32 + quad * 8);
            acc[ot] = __builtin_amdgcn_mfma_f32_16x16x32_bf16(a, wb, acc[ot], 0, 0, 0);
        }
        if (ch < 7) {
            xs[buf ^ 1][na][ca] = bf16_rne(la);
            xs[buf ^ 1][nb2][cb] = bf16_rne(lb);
        }
        __syncthreads();
    }
    const int n = n0 + ws * 16 + quad * 4;
#pragma unroll
    for (int ot = 0; ot < 5; ++ot) {
        const int gro = oq * 5 + ot;
        if (gro < 4) {
            const int o = gro * 16 + l15;
#pragma unroll
            for (int r = 0; r < 4; ++r)
                qkT[((size_t)b * N_ + n + r) * C4_ + o] = bf16_rne(acc[ot][r]);
        } else {
            const int c = (gro - 4) * 16 + l15;
            const float bb = bv[c];
            ushort4 u;
            u.x = bf16_rne(acc[ot][0] + bb);
            u.y = bf16_rne(acc[ot][1] + bb);
            u.z = bf16_rne(acc[ot][2] + bb);
            u.w = bf16_rne(acc[ot][3] + bb);
            *reinterpret_cast<ushort4*>(&v[((size_t)b * C_ + c) * N_ + n]) = u;
        }
    }
}

// rowsuminv[b,n] = 1/sum_m exp(e[n,m]). 16 waves = 4 n-strips x 4 m-subtiles,
// all walking the same m-tile staged into LDS (dbuf) with coalesced loads.
__global__ __launch_bounds__(1024, 4) void rowsum_kernel(
        const unsigned short* __restrict__ qkT, float* __restrict__ rowsuminv) {
    __shared__ unsigned short kt[2][64][68];
    __shared__ float red[4][4][16];
    const int b = blockIdx.y;
    const int tid = threadIdx.x;
    const int wave = tid >> 6, lane = tid & 63;
    const int ws = wave & 3, sg = wave >> 2;
    const int quad = lane >> 4, l15 = lane & 15;
    const int n0 = blockIdx.x * 64;
    const unsigned short* qb = qkT + (size_t)b * N_ * C4_;
    const unsigned short* qrow = qb + (size_t)(n0 + ws * 16 + l15) * C4_;
    const bf16x8 a0 = *reinterpret_cast<const bf16x8*>(qrow + quad * 8);
    const bf16x8 a1 = *reinterpret_cast<const bf16x8*>(qrow + 32 + quad * 8);
    const int srow = tid >> 3, soff = tid & 7;
    if (tid < 512) {
        const bf16x8 sk = *reinterpret_cast<const bf16x8*>(qb + (size_t)srow * C4_ + soff * 8);
        *reinterpret_cast<bf16x8*>(&kt[0][srow][soff * 8]) = sk;
    }
    __syncthreads();
    float cs[4] = {};
    for (int mt = 0; mt < 64; ++mt) {
        const int buf = mt & 1;
        bf16x8 nk;
        if (mt < 63 && tid < 512)
            nk = *reinterpret_cast<const bf16x8*>(
                qb + (size_t)((mt + 1) * 64 + srow) * C4_ + soff * 8);
        const bf16x8 kb0 = *reinterpret_cast<const bf16x8*>(&kt[buf][sg * 16 + l15][quad * 8]);
        const bf16x8 kb1 = *reinterpret_cast<const bf16x8*>(&kt[buf][sg * 16 + l15][32 + quad * 8]);
        f32x4 z = {0.f, 0.f, 0.f, 0.f};
        z = __builtin_amdgcn_mfma_f32_16x16x32_bf16(a0, kb0, z, 0, 0, 0);
        const f32x4 e = __builtin_amdgcn_mfma_f32_16x16x32_bf16(a1, kb1, z, 0, 0, 0);
#pragma unroll
        for (int r = 0; r < 4; ++r) cs[r] += __expf(e[r]);
        if (mt < 63 && tid < 512)
            *reinterpret_cast<bf16x8*>(&kt[buf ^ 1][srow][soff * 8]) = nk;
        __syncthreads();
    }
#pragma unroll
    for (int r = 0; r < 4; ++r) {
#pragma unroll
        for (int k = 1; k <= 8; k <<= 1) cs[r] += __shfl_xor(cs[r], k, 64);
        if (l15 == 0) red[sg][ws][quad * 4 + r] = cs[r];
    }
    __syncthreads();
    if (tid < 64) {
        const int ws2 = tid >> 4, row = tid & 15;
        const float sum = red[0][ws2][row] + red[1][ws2][row] +
                          red[2][ws2][row] + red[3][ws2][row];
        rowsuminv[(size_t)b * N_ + n0 + ws2 * 16 + row] = 1.0f / sum;
    }
}

// colsuminv[b,m] = 1/(1e-9 + sum_n exp(e[n,m])*rowsuminv[n]).
// 16 waves = 4 m-strips (kb in regs) x 4 n-subtiles of the staged q-tile.
__global__ __launch_bounds__(1024, 4) void colsum_kernel(
        const unsigned short* __restrict__ qkT, const float* __restrict__ rowsuminv,
        float* __restrict__ colsuminv) {
    __shared__ float rl[N_];
    __shared__ unsigned short qt[2][64][68];
    __shared__ float red[4][4][16];
    const int b = blockIdx.y;
    const int tid = threadIdx.x;
    const int wave = tid >> 6, lane = tid & 63;
    const int mw = wave & 3, ng = wave >> 2;
    const int quad = lane >> 4, l15 = lane & 15;
    const int m0 = blockIdx.x * 64;
    for (int i = tid; i < N_; i += 1024) rl[i] = rowsuminv[(size_t)b * N_ + i];
    const unsigned short* qb = qkT + (size_t)b * N_ * C4_;
    const unsigned short* krow = qb + (size_t)(m0 + mw * 16 + l15) * C4_;
    const bf16x8 kb0 = *reinterpret_cast<const bf16x8*>(krow + quad * 8);
    const bf16x8 kb1 = *reinterpret_cast<const bf16x8*>(krow + 32 + quad * 8);
    const int srow = tid >> 3, soff = tid & 7;
    if (tid < 512) {
        const bf16x8 sq = *reinterpret_cast<const bf16x8*>(qb + (size_t)srow * C4_ + soff * 8);
        *reinterpret_cast<bf16x8*>(&qt[0][srow][soff * 8]) = sq;
    }
    __syncthreads();
    float cs = 0.f;
    for (int nt = 0; nt < 64; ++nt) {
        const int buf = nt & 1;
        bf16x8 nq;
        if (nt < 63 && tid < 512)
            nq = *reinterpret_cast<const bf16x8*>(
                qb + (size_t)((nt + 1) * 64 + srow) * C4_ + soff * 8);
        const bf16x8 a0 = *reinterpret_cast<const bf16x8*>(&qt[buf][ng * 16 + l15][quad * 8]);
        const bf16x8 a1 = *reinterpret_cast<const bf16x8*>(&qt[buf][ng * 16 + l15][32 + quad * 8]);
        f32x4 z = {0.f, 0.f, 0.f, 0.f};
        z = __builtin_amdgcn_mfma_f32_16x16x32_bf16(a0, kb0, z, 0, 0, 0);
        const f32x4 e = __builtin_amdgcn_mfma_f32_16x16x32_bf16(a1, kb1, z, 0, 0, 0);
        const int nb = nt * 64 + ng * 16 + quad * 4;
#pragma unroll
        for (int r = 0; r < 4; ++r) cs += __expf(e[r]) * rl[nb + r];
        if (nt < 63 && tid < 512)
            *reinterpret_cast<bf16x8*>(&qt[buf ^ 1][srow][soff * 8]) = nq;
        __syncthreads();
    }
    cs += __shfl_xor(cs, 16, 64);
    cs += __shfl_xor(cs, 32, 64);
    if (quad == 0) red[ng][mw][l15] = cs;
    __syncthreads();
    if (tid < 64) {
        const int mw2 = tid >> 4, l = tid & 15;
        const float sum = red[0][mw2][l] + red[1][mw2][l] +
                          red[2][mw2][l] + red[3][mw2][l];
        colsuminv[(size_t)b * N_ + m0 + mw2 * 16 + l] = 1.0f / (1e-9f + sum);
    }
}

// Final v3: 512-thread blocks (8 waves = 2 n-strips x 4 roles), n-tile 32,
// grid 512 -> TWO independent blocks per CU (LDS 57 KB), same-batch pairs
// per XCD. Per 64-m tile: A issue stage loads; B energy (swapped mfma(K,Q),
// kt dbuf) -> p; C lgkm+bar; D PV from single-buffered vt; E lgkm+bar;
// F write stage (vmcnt lands here); G lgkm+bar. colsuminv read direct
// (L2-hot). Epilogue: dsm -> wt GEMM -> BN -> relu (verified path).
__global__ __launch_bounds__(512, 4) void final_kernel(
        const float* __restrict__ x, const unsigned short* __restrict__ qkT,
        const unsigned short* __restrict__ v, const unsigned short* __restrict__ wtb,
        const float* __restrict__ rowsuminv, const float* __restrict__ colsuminv,
        const float* __restrict__ bt, const float* __restrict__ gamma,
        const float* __restrict__ beta, const float* __restrict__ rmean,
        const float* __restrict__ rvar, float* __restrict__ out) {
    __shared__ union {
        unsigned short vt[256][68];                                     // 34.0 KB
        unsigned short dsm[32][268];                                    // 16.8 KB
    } u;
    __shared__ unsigned short kt[2][64][68];                            // 17.0 KB
    __shared__ unsigned short p_sh[2][16][68];                          //  4.3 KB
    const int gid = blockIdx.x;
    const int xcd = gid & 7;
    const int b = xcd >> 1;                       // batch -> XCD pair (L2 fit)
    const int n0 = ((((unsigned)gid >> 3) << 1) | (xcd & 1)) * 32;
    const int tid = threadIdx.x;
    const int wave = tid >> 6, lane = tid & 63;
    const int ws = wave & 1, g = wave >> 1;
    const int quad = lane >> 4, l15 = lane & 15;
    const unsigned short* qb = qkT + (size_t)b * N_ * C4_;
    const unsigned short* vbg = v + (size_t)b * C_ * N_;
    const float* civb = colsuminv + (size_t)b * N_;
    // q fragments + rowsuminv for this wave's n-strip
    const unsigned short* qrow = qb + (size_t)(n0 + ws * 16 + l15) * C4_;
    const bf16x8 q0 = *reinterpret_cast<const bf16x8*>(qrow + quad * 8);
    const bf16x8 q1 = *reinterpret_cast<const bf16x8*>(qrow + 32 + quad * 8);
    const float rli = rowsuminv[(size_t)b * N_ + n0 + ws * 16 + l15];
    // staging geometry: vt = 256 rows x 64 m (2 threads/row, 4 b128 each);
    // kt = 64 rows x 64 ch (1 b128/thread)
    const int vrow = tid >> 1, vhalf = tid & 1;
    const int srow = tid >> 3, soff = tid & 7;
    // prologue: stage tile 0
    {
#pragma unroll
        for (int k = 0; k < 4; ++k) {
            const bf16x8 sv = *reinterpret_cast<const bf16x8*>(
                vbg + (size_t)vrow * N_ + vhalf * 32 + k * 8);
            *reinterpret_cast<bf16x8*>(&u.vt[vrow][vhalf * 32 + k * 8]) = sv;
        }
        const bf16x8 sk = *reinterpret_cast<const bf16x8*>(qb + (size_t)srow * C4_ + soff * 8);
        *reinterpret_cast<bf16x8*>(&kt[0][srow][soff * 8]) = sk;
    }
    __syncthreads();
    f32x4 acc[4];
#pragma unroll
    for (int j = 0; j < 4; ++j) acc[j] = (f32x4){0.f, 0.f, 0.f, 0.f};
#pragma unroll 1
    for (int mt = 0; mt < 64; ++mt) {
        const int buf = mt & 1;
        const int m0 = mt * 64;
        // A: issue next-tile stage loads (consumed at F)
        bf16x8 nv[4], nk;
        if (mt < 63) {
#pragma unroll
            for (int k = 0; k < 4; ++k)
                nv[k] = *reinterpret_cast<const bf16x8*>(
                    vbg + (size_t)vrow * N_ + m0 + 64 + vhalf * 32 + k * 8);
            nk = *reinterpret_cast<const bf16x8*>(
                qb + (size_t)(m0 + 64 + srow) * C4_ + soff * 8);
        }
        // B: energy for (ws strip, g m-subtile): swapped mfma(K,Q).
        // lane holds e[n=l15][m = m0 + g*16 + quad*4 + r]
        {
            const bf16x8 ka0 = *reinterpret_cast<const bf16x8*>(&kt[buf][g * 16 + l15][quad * 8]);
            const bf16x8 ka1 = *reinterpret_cast<const bf16x8*>(&kt[buf][g * 16 + l15][32 + quad * 8]);
            f32x4 z = {0.f, 0.f, 0.f, 0.f};
            z = __builtin_amdgcn_mfma_f32_16x16x32_bf16(ka0, q0, z, 0, 0, 0);
            z = __builtin_amdgcn_mfma_f32_16x16x32_bf16(ka1, q1, z, 0, 0, 0);
            const float4 civ = *reinterpret_cast<const float4*>(civb + m0 + g * 16 + quad * 4);
            ushort4 pk;
            pk.x = bf16_rne(__expf(z[0]) * rli * civ.x);
            pk.y = bf16_rne(__expf(z[1]) * rli * civ.y);
            pk.z = bf16_rne(__expf(z[2]) * rli * civ.z);
            pk.w = bf16_rne(__expf(z[3]) * rli * civ.w);
            *reinterpret_cast<ushort4*>(&p_sh[ws][l15][g * 16 + quad * 4]) = pk;
        }
        // C: p ready (cross-wave within strip) -- LDS fence + raw barrier
        asm volatile("s_waitcnt lgkmcnt(0)" ::: "memory");
        __builtin_amdgcn_s_barrier();
        // D: PV for (ws strip, g channel-quarter) from single-buffered vt
        {
            const bf16x8 pa0 = *reinterpret_cast<const bf16x8*>(&p_sh[ws][l15][quad * 8]);
            const bf16x8 pa1 = *reinterpret_cast<const bf16x8*>(&p_sh[ws][l15][32 + quad * 8]);
#pragma unroll
            for (int j = 0; j < 4; ++j) {
                const int c0 = (g * 4 + j) * 16;
                const bf16x8 vb0 = *reinterpret_cast<const bf16x8*>(&u.vt[c0 + l15][quad * 8]);
                const bf16x8 vb1 = *reinterpret_cast<const bf16x8*>(&u.vt[c0 + l15][32 + quad * 8]);
                acc[j] = __builtin_amdgcn_mfma_f32_16x16x32_bf16(pa0, vb0, acc[j], 0, 0, 0);
                acc[j] = __builtin_amdgcn_mfma_f32_16x16x32_bf16(pa1, vb1, acc[j], 0, 0, 0);
            }
        }
        // E: all PV reads of vt done -- fence + barrier before overwrite
        asm volatile("s_waitcnt lgkmcnt(0)" ::: "memory");
        __builtin_amdgcn_s_barrier();
        // F: write next tile (compiler places vmcnt wait here, ~1 iter later)
        if (mt < 63) {
#pragma unroll
            for (int k = 0; k < 4; ++k)
                *reinterpret_cast<bf16x8*>(&u.vt[vrow][vhalf * 32 + k * 8]) = nv[k];
            *reinterpret_cast<bf16x8*>(&kt[buf ^ 1][srow][soff * 8]) = nk;
        }
        // G: stage visible before next B (kt) / D (vt)
        asm volatile("s_waitcnt lgkmcnt(0)" ::: "memory");
        __builtin_amdgcn_s_barrier();
    }
    // dsm = x - x_r (bf16); acc[j][r] = x_r[n=ws*16+quad*4+r][c=(g*4+j)*16+l15]
#pragma unroll
    for (int j = 0; j < 4; ++j) {
        const int c = (g * 4 + j) * 16 + l15;
        const float4 xv = *reinterpret_cast<const float4*>(
            &x[((size_t)b * C_ + c) * N_ + n0 + ws * 16 + quad * 4]);
        const float xvr[4] = {xv.x, xv.y, xv.z, xv.w};
#pragma unroll
        for (int r = 0; r < 4; ++r)
            u.dsm[ws * 16 + quad * 4 + r][c] = bf16_rne(xvr[r] - acc[j][r]);
    }
    __syncthreads();
    // wt GEMM: 2 strips x 4 o-quarters
    bf16x8 da[8];
#pragma unroll
    for (int k = 0; k < 8; ++k)
        da[k] = *reinterpret_cast<const bf16x8*>(&u.dsm[ws * 16 + l15][k * 32 + quad * 8]);
    f32x4 tacc[4];
#pragma unroll
    for (int j = 0; j < 4; ++j) tacc[j] = (f32x4){0.f, 0.f, 0.f, 0.f};
#pragma unroll
    for (int j = 0; j < 4; ++j) {
        const int ot = g * 4 + j;
#pragma unroll
        for (int k = 0; k < 8; ++k) {
            const bf16x8 wb = *reinterpret_cast<const bf16x8*>(
                wtb + (size_t)(ot * 16 + l15) * C_ + k * 32 + quad * 8);
            tacc[j] = __builtin_amdgcn_mfma_f32_16x16x32_bf16(da[k], wb, tacc[j], 0, 0, 0);
        }
    }
#pragma unroll
    for (int j = 0; j < 4; ++j) {
        const int o = (g * 4 + j) * 16 + l15;
        const float gg = gamma[o] * rsqrtf(rvar[o] + 1e-5f);
        const float mn = rmean[o], bbet = beta[o], bo = bt[o];
        const size_t oi = ((size_t)b * C_ + o) * N_ + n0 + ws * 16 + quad * 4;
        const float4 xo = *reinterpret_cast<const float4*>(&x[oi]);
        float4 res;
        res.x = xo.x + fmaxf((tacc[j][0] + bo - mn) * gg + bbet, 0.f);
        res.y = xo.y + fmaxf((tacc[j][1] + bo - mn) * gg + bbet, 0.f);
        res.z = xo.z + fmaxf((tacc[j][2] + bo - mn) * gg + bbet, 0.f);
        res.w = xo.w + fmaxf((tacc[j][3] + bo - mn) * gg + bbet, 0.f);
        *reinterpret_cast<float4*>(&out[oi]) = res;
    }
}

}  // namespace

extern "C" void kernel_launch(void* const* d_in, const int* in_sizes, int n_in,
                              void* d_out, int out_size, void* d_ws, size_t ws_size,
                              hipStream_t stream) {
    const float* x = (const float*)d_in[0];
    const float* wq = (const float*)d_in[1];
    const float* wv = (const float*)d_in[2];
    const float* bv = (const float*)d_in[3];
    const float* wt = (const float*)d_in[4];
    const float* bt = (const float*)d_in[5];
    const float* gamma = (const float*)d_in[6];
    const float* beta = (const float*)d_in[7];
    const float* rmean = (const float*)d_in[8];
    const float* rvar = (const float*)d_in[9];
    float* out = (float*)d_out;

    char* base = (char*)d_ws;
    unsigned short* qkT = (unsigned short*)base;                        // 2 MB
    unsigned short* vw = (unsigned short*)(base + (2u << 20));          // 8 MB
    unsigned short* wtb = (unsigned short*)(base + (10u << 20));        // 128 KB
    unsigned short* wcomb = (unsigned short*)(base + (10u << 20) + (128u << 10));
    float* rowsuminv = (float*)(base + (10u << 20) + (288u << 10));     // 64 KB
    float* colsuminv = (float*)(base + (10u << 20) + (352u << 10));     // 64 KB

    cvt_kernel<<<dim3(144), dim3(256), 0, stream>>>(wq, wv, wt, wcomb, wtb);
    proj_kernel<<<dim3(N_ / 64, B_), dim3(1024), 0, stream>>>(x, wcomb, bv, qkT, vw);
    rowsum_kernel<<<dim3(N_ / 64, B_), dim3(1024), 0, stream>>>(qkT, rowsuminv);
    colsum_kernel<<<dim3(N_ / 64, B_), dim3(1024), 0, stream>>>(qkT, rowsuminv, colsuminv);
    final_kernel<<<dim3(N_ / 32 * B_), dim3(512), 0, stream>>>(
        x, qkT, vw, wtb, rowsuminv, colsuminv, bt, gamma, beta, rmean, rvar, out);
}

// Round 4
// 267.897 us; speedup vs baseline: 2.0962x; 2.0962x over previous
//
#include <hip/hip_runtime.h>
#include <math.h>

namespace {

constexpr int B_ = 4;
constexpr int C_ = 256;
constexpr int C4_ = 64;
constexpr int N_ = 4096;

typedef __attribute__((ext_vector_type(8))) short bf16x8;
typedef __attribute__((ext_vector_type(4))) float f32x4;

__device__ __forceinline__ unsigned short bf16_rne(float f) {
    unsigned u = __float_as_uint(f);
    u += 0x7fffu + ((u >> 16) & 1u);
    return (unsigned short)(u >> 16);
}

// Async global->LDS DMA, 16B per lane. LDS dest = wave-uniform base + lane*16.
__device__ __forceinline__ void g2l16(const unsigned short* g, unsigned short* l) {
    __builtin_amdgcn_global_load_lds(
        (const __attribute__((address_space(1))) unsigned int*)g,
        (__attribute__((address_space(3))) unsigned int*)l, 16, 0, 0);
}

// Convert wq||wv -> wcomb bf16 [320,256], wt -> wtb bf16 [256,256].
__global__ __launch_bounds__(256) void cvt_kernel(
        const float* __restrict__ wq, const float* __restrict__ wv,
        const float* __restrict__ wt, unsigned short* __restrict__ wcomb,
        unsigned short* __restrict__ wtb) {
    const int i = (blockIdx.x * 256 + threadIdx.x) * 4;
    const float* src;
    unsigned short* dst;
    if (i < 16384) { src = wq + i; dst = wcomb + i; }
    else if (i < 81920) { src = wv + (i - 16384); dst = wcomb + i; }
    else { src = wt + (i - 81920); dst = wtb + (i - 81920); }
    const float4 f = *reinterpret_cast<const float4*>(src);
    ushort4 u;
    u.x = bf16_rne(f.x); u.y = bf16_rne(f.y);
    u.z = bf16_rne(f.z); u.w = bf16_rne(f.w);
    *reinterpret_cast<ushort4*>(dst) = u;
}

// MFMA projection: one 1024-thread block per 64-n tile; 16 waves = 4 n-strips
// x 4 o-quarters (5 ot each). x staged once per block.
__global__ __launch_bounds__(1024, 4) void proj_kernel(
        const float* __restrict__ x, const unsigned short* __restrict__ wcomb,
        const float* __restrict__ bv, unsigned short* __restrict__ qkT,
        unsigned short* __restrict__ v) {
    __shared__ unsigned short xs[2][64][40];
    const int b = blockIdx.y;
    const int n0 = blockIdx.x * 64;
    const int tid = threadIdx.x;
    const int wave = tid >> 6, lane = tid & 63;
    const int ws = wave & 3, oq = wave >> 2;
    const int quad = lane >> 4, l15 = lane & 15;
    const int ca = tid >> 6, na = tid & 63;
    const int cb = (tid + 1024) >> 6, nb2 = (tid + 1024) & 63;
    f32x4 acc[5];
#pragma unroll
    for (int ot = 0; ot < 5; ++ot) acc[ot] = (f32x4){0.f, 0.f, 0.f, 0.f};
    xs[0][na][ca] = bf16_rne(x[((size_t)b * C_ + ca) * N_ + n0 + na]);
    xs[0][nb2][cb] = bf16_rne(x[((size_t)b * C_ + cb) * N_ + n0 + nb2]);
    __syncthreads();
    for (int ch = 0; ch < 8; ++ch) {
        const int buf = ch & 1;
        float la = 0.f, lb = 0.f;
        if (ch < 7) {
            la = x[((size_t)b * C_ + (ch + 1) * 32 + ca) * N_ + n0 + na];
            lb = x[((size_t)b * C_ + (ch + 1) * 32 + cb) * N_ + n0 + nb2];
        }
        const bf16x8 a = *reinterpret_cast<const bf16x8*>(&xs[buf][ws * 16 + l15][quad * 8]);
#pragma unroll
        for (int ot = 0; ot < 5; ++ot) {
            const int gro = oq * 5 + ot;
            const bf16x8 wb = *reinterpret_cast<const bf16x8*>(
                wcomb + (size_t)(gro * 16 + l15) * C_ + ch * 32 + quad * 8);
            acc[ot] = __builtin_amdgcn_mfma_f32_16x16x32_bf16(a, wb, acc[ot], 0, 0, 0);
        }
        if (ch < 7) {
            xs[buf ^ 1][na][ca] = bf16_rne(la);
            xs[buf ^ 1][nb2][cb] = bf16_rne(lb);
        }
        __syncthreads();
    }
    const int n = n0 + ws * 16 + quad * 4;
#pragma unroll
    for (int ot = 0; ot < 5; ++ot) {
        const int gro = oq * 5 + ot;
        if (gro < 4) {
            const int o = gro * 16 + l15;
#pragma unroll
            for (int r = 0; r < 4; ++r)
                qkT[((size_t)b * N_ + n + r) * C4_ + o] = bf16_rne(acc[ot][r]);
        } else {
            const int c = (gro - 4) * 16 + l15;
            const float bb = bv[c];
            ushort4 u;
            u.x = bf16_rne(acc[ot][0] + bb);
            u.y = bf16_rne(acc[ot][1] + bb);
            u.z = bf16_rne(acc[ot][2] + bb);
            u.w = bf16_rne(acc[ot][3] + bb);
            *reinterpret_cast<ushort4*>(&v[((size_t)b * C_ + c) * N_ + n]) = u;
        }
    }
}

// rowsuminv[b,n] = 1/sum_m exp(e[n,m]). 16 waves = 4 n-strips x 4 m-subtiles,
// all walking the same m-tile staged into LDS (dbuf) with coalesced loads.
__global__ __launch_bounds__(1024, 4) void rowsum_kernel(
        const unsigned short* __restrict__ qkT, float* __restrict__ rowsuminv) {
    __shared__ unsigned short kt[2][64][68];
    __shared__ float red[4][4][16];
    const int b = blockIdx.y;
    const int tid = threadIdx.x;
    const int wave = tid >> 6, lane = tid & 63;
    const int ws = wave & 3, sg = wave >> 2;
    const int quad = lane >> 4, l15 = lane & 15;
    const int n0 = blockIdx.x * 64;
    const unsigned short* qb = qkT + (size_t)b * N_ * C4_;
    const unsigned short* qrow = qb + (size_t)(n0 + ws * 16 + l15) * C4_;
    const bf16x8 a0 = *reinterpret_cast<const bf16x8*>(qrow + quad * 8);
    const bf16x8 a1 = *reinterpret_cast<const bf16x8*>(qrow + 32 + quad * 8);
    const int srow = tid >> 3, soff = tid & 7;
    if (tid < 512) {
        const bf16x8 sk = *reinterpret_cast<const bf16x8*>(qb + (size_t)srow * C4_ + soff * 8);
        *reinterpret_cast<bf16x8*>(&kt[0][srow][soff * 8]) = sk;
    }
    __syncthreads();
    float cs[4] = {};
    for (int mt = 0; mt < 64; ++mt) {
        const int buf = mt & 1;
        bf16x8 nk;
        if (mt < 63 && tid < 512)
            nk = *reinterpret_cast<const bf16x8*>(
                qb + (size_t)((mt + 1) * 64 + srow) * C4_ + soff * 8);
        const bf16x8 kb0 = *reinterpret_cast<const bf16x8*>(&kt[buf][sg * 16 + l15][quad * 8]);
        const bf16x8 kb1 = *reinterpret_cast<const bf16x8*>(&kt[buf][sg * 16 + l15][32 + quad * 8]);
        f32x4 z = {0.f, 0.f, 0.f, 0.f};
        z = __builtin_amdgcn_mfma_f32_16x16x32_bf16(a0, kb0, z, 0, 0, 0);
        const f32x4 e = __builtin_amdgcn_mfma_f32_16x16x32_bf16(a1, kb1, z, 0, 0, 0);
#pragma unroll
        for (int r = 0; r < 4; ++r) cs[r] += __expf(e[r]);
        if (mt < 63 && tid < 512)
            *reinterpret_cast<bf16x8*>(&kt[buf ^ 1][srow][soff * 8]) = nk;
        __syncthreads();
    }
#pragma unroll
    for (int r = 0; r < 4; ++r) {
#pragma unroll
        for (int k = 1; k <= 8; k <<= 1) cs[r] += __shfl_xor(cs[r], k, 64);
        if (l15 == 0) red[sg][ws][quad * 4 + r] = cs[r];
    }
    __syncthreads();
    if (tid < 64) {
        const int ws2 = tid >> 4, row = tid & 15;
        const float sum = red[0][ws2][row] + red[1][ws2][row] +
                          red[2][ws2][row] + red[3][ws2][row];
        rowsuminv[(size_t)b * N_ + n0 + ws2 * 16 + row] = 1.0f / sum;
    }
}

// colsuminv[b,m] = 1/(1e-9 + sum_n exp(e[n,m])*rowsuminv[n]).
// 16 waves = 4 m-strips (kb in regs) x 4 n-subtiles of the staged q-tile.
__global__ __launch_bounds__(1024, 4) void colsum_kernel(
        const unsigned short* __restrict__ qkT, const float* __restrict__ rowsuminv,
        float* __restrict__ colsuminv) {
    __shared__ float rl[N_];
    __shared__ unsigned short qt[2][64][68];
    __shared__ float red[4][4][16];
    const int b = blockIdx.y;
    const int tid = threadIdx.x;
    const int wave = tid >> 6, lane = tid & 63;
    const int mw = wave & 3, ng = wave >> 2;
    const int quad = lane >> 4, l15 = lane & 15;
    const int m0 = blockIdx.x * 64;
    for (int i = tid; i < N_; i += 1024) rl[i] = rowsuminv[(size_t)b * N_ + i];
    const unsigned short* qb = qkT + (size_t)b * N_ * C4_;
    const unsigned short* krow = qb + (size_t)(m0 + mw * 16 + l15) * C4_;
    const bf16x8 kb0 = *reinterpret_cast<const bf16x8*>(krow + quad * 8);
    const bf16x8 kb1 = *reinterpret_cast<const bf16x8*>(krow + 32 + quad * 8);
    const int srow = tid >> 3, soff = tid & 7;
    if (tid < 512) {
        const bf16x8 sq = *reinterpret_cast<const bf16x8*>(qb + (size_t)srow * C4_ + soff * 8);
        *reinterpret_cast<bf16x8*>(&qt[0][srow][soff * 8]) = sq;
    }
    __syncthreads();
    float cs = 0.f;
    for (int nt = 0; nt < 64; ++nt) {
        const int buf = nt & 1;
        bf16x8 nq;
        if (nt < 63 && tid < 512)
            nq = *reinterpret_cast<const bf16x8*>(
                qb + (size_t)((nt + 1) * 64 + srow) * C4_ + soff * 8);
        const bf16x8 a0 = *reinterpret_cast<const bf16x8*>(&qt[buf][ng * 16 + l15][quad * 8]);
        const bf16x8 a1 = *reinterpret_cast<const bf16x8*>(&qt[buf][ng * 16 + l15][32 + quad * 8]);
        f32x4 z = {0.f, 0.f, 0.f, 0.f};
        z = __builtin_amdgcn_mfma_f32_16x16x32_bf16(a0, kb0, z, 0, 0, 0);
        const f32x4 e = __builtin_amdgcn_mfma_f32_16x16x32_bf16(a1, kb1, z, 0, 0, 0);
        const int nb = nt * 64 + ng * 16 + quad * 4;
#pragma unroll
        for (int r = 0; r < 4; ++r) cs += __expf(e[r]) * rl[nb + r];
        if (nt < 63 && tid < 512)
            *reinterpret_cast<bf16x8*>(&qt[buf ^ 1][srow][soff * 8]) = nq;
        __syncthreads();
    }
    cs += __shfl_xor(cs, 16, 64);
    cs += __shfl_xor(cs, 32, 64);
    if (quad == 0) red[ng][mw][l15] = cs;
    __syncthreads();
    if (tid < 64) {
        const int mw2 = tid >> 4, l = tid & 15;
        const float sum = red[0][mw2][l] + red[1][mw2][l] +
                          red[2][mw2][l] + red[3][mw2][l];
        colsuminv[(size_t)b * N_ + m0 + mw2 * 16 + l] = 1.0f / (1e-9f + sum);
    }
}

// Final v4: global_load_lds DMA staging, TRIPLE-buffered vt/kt, counted vmcnt
// (never 0 in steady state), 2 barriers/iter. LDS rows are linear 128B (DMA
// constraint) with XOR swizzle col^=((row&7)<<4) applied BOTH at the global
// source address (stage) and at every ds_read (T2 / rule #21). 16 waves =
// 4 n-strips (ws) x 4 roles (g). Epilogue: dsm -> wt GEMM -> BN -> relu.
__global__ __launch_bounds__(1024, 4) void final_kernel(
        const float* __restrict__ x, const unsigned short* __restrict__ qkT,
        const unsigned short* __restrict__ v, const unsigned short* __restrict__ wtb,
        const float* __restrict__ rowsuminv, const float* __restrict__ colsuminv,
        const float* __restrict__ bt, const float* __restrict__ gamma,
        const float* __restrict__ beta, const float* __restrict__ rmean,
        const float* __restrict__ rvar, float* __restrict__ out) {
    __shared__ union {
        struct {
            unsigned short vt[3][256][64];                              // 96 KB
            unsigned short kt[3][64][64];                               // 24 KB
        } s;
        unsigned short dsm[64][268];                                    // 33.5 KB
    } u;
    __shared__ unsigned short p_sh[4][16][68];                          //  8.5 KB
    __shared__ float ci[N_];                                            // 16 KB
    const int gid = blockIdx.x;
    const int xcd = gid & 7;
    const int b = xcd >> 1;                       // batch -> XCD pair (L2 fit)
    const int n0 = ((((unsigned)gid >> 3) << 1) | (xcd & 1)) * 64;
    const int tid = threadIdx.x;
    const int wave = tid >> 6, lane = tid & 63;
    const int ws = wave & 3, g = wave >> 2;
    const int quad = lane >> 4, l15 = lane & 15;
    const unsigned short* qb = qkT + (size_t)b * N_ * C4_;
    const unsigned short* vbg = v + (size_t)b * C_ * N_;
    // DMA staging geometry: wave w stages 1KB chunks; lane l -> dest byte
    // base+16l = row (w*8 + l>>3), col shorts (l&7)*8. Global source col is
    // pre-swizzled so that LDS[row][c] holds global (row, c ^ ((row&7)<<3)sh).
    const int rowA = lane >> 3;                  // 0..7  (== row&7 of dest row)
    const int swc = ((lane & 7) ^ rowA) * 8;     // swizzled source col (shorts)
    const int w8 = wave * 8;
    // swizzled read cols (shorts) for 128B rows: logical cols quad*8, 32+quad*8
    const int r7 = l15 & 7;
    const int c0s = (quad * 8) ^ (r7 << 3);
    const int c1s = (32 + quad * 8) ^ (r7 << 3);
    // prologue: q fragments, rowsuminv, colsuminv->LDS (all VMEM consumed
    // before the counted-DMA regime starts)
    const unsigned short* qrow = qb + (size_t)(n0 + ws * 16 + l15) * C4_;
    const bf16x8 q0 = *reinterpret_cast<const bf16x8*>(qrow + quad * 8);
    const bf16x8 q1 = *reinterpret_cast<const bf16x8*>(qrow + 32 + quad * 8);
    const float rli = rowsuminv[(size_t)b * N_ + n0 + ws * 16 + l15];
    {
        const float4 c4 = *reinterpret_cast<const float4*>(colsuminv + (size_t)b * N_ + tid * 4);
        *reinterpret_cast<float4*>(&ci[tid * 4]) = c4;
    }
    // stage tiles 0 and 1 via DMA (per wave: 2 vt + (wave<8: 1 kt) per tile)
#define STAGE_TILE(sidx, bufS)                                                          \
    do {                                                                                \
        g2l16(vbg + (size_t)(w8 + rowA) * N_ + (sidx) * 64 + swc,                       \
              &u.s.vt[bufS][w8][0]);                                                    \
        g2l16(vbg + (size_t)(w8 + 128 + rowA) * N_ + (sidx) * 64 + swc,                 \
              &u.s.vt[bufS][w8 + 128][0]);                                              \
        if (wave < 8)                                                                   \
            g2l16(qb + (size_t)((sidx) * 64 + w8 + rowA) * C4_ + swc,                   \
                  &u.s.kt[bufS][w8][0]);                                                \
    } while (0)
    STAGE_TILE(0, 0);
    STAGE_TILE(1, 1);
    if (wave < 8) asm volatile("s_waitcnt vmcnt(3)" ::: "memory");
    else          asm volatile("s_waitcnt vmcnt(2)" ::: "memory");
    asm volatile("s_waitcnt lgkmcnt(0)" ::: "memory");
    __builtin_amdgcn_s_barrier();
    f32x4 acc[4];
#pragma unroll
    for (int j = 0; j < 4; ++j) acc[j] = (f32x4){0.f, 0.f, 0.f, 0.f};
    int bufR = 0;
#pragma unroll 1
    for (int t = 0; t < 64; ++t) {
        // issue stage(t+2) into the buffer no one reads this iteration
        if (t <= 61) {
            int bufS = bufR + 2; if (bufS >= 3) bufS -= 3;
            STAGE_TILE(t + 2, bufS);
        }
        // B: energy for (ws strip, g m-subtile): swapped mfma(K,Q).
        // lane holds e[n=l15][m = t*64 + g*16 + quad*4 + r]
        {
            const unsigned short(*ktb)[64] = u.s.kt[bufR];
            const bf16x8 ka0 = *reinterpret_cast<const bf16x8*>(&ktb[g * 16 + l15][c0s]);
            const bf16x8 ka1 = *reinterpret_cast<const bf16x8*>(&ktb[g * 16 + l15][c1s]);
            f32x4 z = {0.f, 0.f, 0.f, 0.f};
            z = __builtin_amdgcn_mfma_f32_16x16x32_bf16(ka0, q0, z, 0, 0, 0);
            z = __builtin_amdgcn_mfma_f32_16x16x32_bf16(ka1, q1, z, 0, 0, 0);
            const float4 civ = *reinterpret_cast<const float4*>(&ci[t * 64 + g * 16 + quad * 4]);
            ushort4 pk;
            pk.x = bf16_rne(__expf(z[0]) * rli * civ.x);
            pk.y = bf16_rne(__expf(z[1]) * rli * civ.y);
            pk.z = bf16_rne(__expf(z[2]) * rli * civ.z);
            pk.w = bf16_rne(__expf(z[3]) * rli * civ.w);
            *reinterpret_cast<ushort4*>(&p_sh[ws][l15][g * 16 + quad * 4]) = pk;
        }
        // C: p ready -- LDS fence + raw barrier (DMA stays in flight)
        asm volatile("s_waitcnt lgkmcnt(0)" ::: "memory");
        __builtin_amdgcn_s_barrier();
        // D: PV for (ws strip, g channel-quarter) over this m-tile
        {
            const bf16x8 pa0 = *reinterpret_cast<const bf16x8*>(&p_sh[ws][l15][quad * 8]);
            const bf16x8 pa1 = *reinterpret_cast<const bf16x8*>(&p_sh[ws][l15][32 + quad * 8]);
            const unsigned short(*vtb)[64] = u.s.vt[bufR];
#pragma unroll
            for (int j = 0; j < 4; ++j) {
                const int vr = (g * 4 + j) * 16 + l15;
                const bf16x8 vb0 = *reinterpret_cast<const bf16x8*>(&vtb[vr][c0s]);
                const bf16x8 vb1 = *reinterpret_cast<const bf16x8*>(&vtb[vr][c1s]);
                acc[j] = __builtin_amdgcn_mfma_f32_16x16x32_bf16(pa0, vb0, acc[j], 0, 0, 0);
                acc[j] = __builtin_amdgcn_mfma_f32_16x16x32_bf16(pa1, vb1, acc[j], 0, 0, 0);
            }
        }
        // F: own LDS reads drained; stage(t+1) landed (counted wait, never 0
        // in steady state -- stage(t+2) remains in flight); release bufR.
        asm volatile("s_waitcnt lgkmcnt(0)" ::: "memory");
        if (t <= 61) {
            if (wave < 8) asm volatile("s_waitcnt vmcnt(3)" ::: "memory");
            else          asm volatile("s_waitcnt vmcnt(2)" ::: "memory");
        } else {
            asm volatile("s_waitcnt vmcnt(0)" ::: "memory");
        }
        __builtin_amdgcn_s_barrier();
        ++bufR; if (bufR >= 3) bufR = 0;
    }
#undef STAGE_TILE
    // dsm = x - x_r (bf16); acc[j][r] = x_r[n=ws*16+quad*4+r][c=(g*4+j)*16+l15]
#pragma unroll
    for (int j = 0; j < 4; ++j) {
        const int c = (g * 4 + j) * 16 + l15;
        const float4 xv = *reinterpret_cast<const float4*>(
            &x[((size_t)b * C_ + c) * N_ + n0 + ws * 16 + quad * 4]);
        const float xvr[4] = {xv.x, xv.y, xv.z, xv.w};
#pragma unroll
        for (int r = 0; r < 4; ++r)
            u.dsm[ws * 16 + quad * 4 + r][c] = bf16_rne(xvr[r] - acc[j][r]);
    }
    __syncthreads();
    // wt GEMM: 4 strips x 4 o-quarters
    bf16x8 da[8];
#pragma unroll
    for (int k = 0; k < 8; ++k)
        da[k] = *reinterpret_cast<const bf16x8*>(&u.dsm[ws * 16 + l15][k * 32 + quad * 8]);
    f32x4 tacc[4];
#pragma unroll
    for (int j = 0; j < 4; ++j) tacc[j] = (f32x4){0.f, 0.f, 0.f, 0.f};
#pragma unroll
    for (int j = 0; j < 4; ++j) {
        const int ot = g * 4 + j;
#pragma unroll
        for (int k = 0; k < 8; ++k) {
            const bf16x8 wb = *reinterpret_cast<const bf16x8*>(
                wtb + (size_t)(ot * 16 + l15) * C_ + k * 32 + quad * 8);
            tacc[j] = __builtin_amdgcn_mfma_f32_16x16x32_bf16(da[k], wb, tacc[j], 0, 0, 0);
        }
    }
#pragma unroll
    for (int j = 0; j < 4; ++j) {
        const int o = (g * 4 + j) * 16 + l15;
        const float gg = gamma[o] * rsqrtf(rvar[o] + 1e-5f);
        const float mn = rmean[o], bbet = beta[o], bo = bt[o];
        const size_t oi = ((size_t)b * C_ + o) * N_ + n0 + ws * 16 + quad * 4;
        const float4 xo = *reinterpret_cast<const float4*>(&x[oi]);
        float4 res;
        res.x = xo.x + fmaxf((tacc[j][0] + bo - mn) * gg + bbet, 0.f);
        res.y = xo.y + fmaxf((tacc[j][1] + bo - mn) * gg + bbet, 0.f);
        res.z = xo.z + fmaxf((tacc[j][2] + bo - mn) * gg + bbet, 0.f);
        res.w = xo.w + fmaxf((tacc[j][3] + bo - mn) * gg + bbet, 0.f);
        *reinterpret_cast<float4*>(&out[oi]) = res;
    }
}

}  // namespace

extern "C" void kernel_launch(void* const* d_in, const int* in_sizes, int n_in,
                              void* d_out, int out_size, void* d_ws, size_t ws_size,
                              hipStream_t stream) {
    const float* x = (const float*)d_in[0];
    const float* wq = (const float*)d_in[1];
    const float* wv = (const float*)d_in[2];
    const float* bv = (const float*)d_in[3];
    const float* wt = (const float*)d_in[4];
    const float* bt = (const float*)d_in[5];
    const float* gamma = (const float*)d_in[6];
    const float* beta = (const float*)d_in[7];
    const float* rmean = (const float*)d_in[8];
    const float* rvar = (const float*)d_in[9];
    float* out = (float*)d_out;

    char* base = (char*)d_ws;
    unsigned short* qkT = (unsigned short*)base;                        // 2 MB
    unsigned short* vw = (unsigned short*)(base + (2u << 20));          // 8 MB
    unsigned short* wtb = (unsigned short*)(base + (10u << 20));        // 128 KB
    unsigned short* wcomb = (unsigned short*)(base + (10u << 20) + (128u << 10));
    float* rowsuminv = (float*)(base + (10u << 20) + (288u << 10));     // 64 KB
    float* colsuminv = (float*)(base + (10u << 20) + (352u << 10));     // 64 KB

    cvt_kernel<<<dim3(144), dim3(256), 0, stream>>>(wq, wv, wt, wcomb, wtb);
    proj_kernel<<<dim3(N_ / 64, B_), dim3(1024), 0, stream>>>(x, wcomb, bv, qkT, vw);
    rowsum_kernel<<<dim3(N_ / 64, B_), dim3(1024), 0, stream>>>(qkT, rowsuminv);
    colsum_kernel<<<dim3(N_ / 64, B_), dim3(1024), 0, stream>>>(qkT, rowsuminv, colsuminv);
    final_kernel<<<dim3(N_ / 64 * B_), dim3(1024), 0, stream>>>(
        x, qkT, vw, wtb, rowsuminv, colsuminv, bt, gamma, beta, rmean, rvar, out);
}

// Round 5
// 260.020 us; speedup vs baseline: 2.1597x; 1.0303x over previous
//
#include <hip/hip_runtime.h>
#include <math.h>

namespace {

constexpr int B_ = 4;
constexpr int C_ = 256;
constexpr int C4_ = 64;
constexpr int N_ = 4096;

typedef __attribute__((ext_vector_type(8))) short bf16x8;
typedef __attribute__((ext_vector_type(4))) float f32x4;

__device__ __forceinline__ unsigned short bf16_rne(float f) {
    unsigned u = __float_as_uint(f);
    u += 0x7fffu + ((u >> 16) & 1u);
    return (unsigned short)(u >> 16);
}

// Async global->LDS DMA, 16B per lane. LDS dest = wave-uniform base + lane*16.
__device__ __forceinline__ void g2l16(const unsigned short* g, unsigned short* l) {
    __builtin_amdgcn_global_load_lds(
        (const __attribute__((address_space(1))) unsigned int*)g,
        (__attribute__((address_space(3))) unsigned int*)l, 16, 0, 0);
}

// Convert wq||wv -> wcomb bf16 [320,256], wt -> wtb bf16 [256,256].
__global__ __launch_bounds__(256) void cvt_kernel(
        const float* __restrict__ wq, const float* __restrict__ wv,
        const float* __restrict__ wt, unsigned short* __restrict__ wcomb,
        unsigned short* __restrict__ wtb) {
    const int i = (blockIdx.x * 256 + threadIdx.x) * 4;
    const float* src;
    unsigned short* dst;
    if (i < 16384) { src = wq + i; dst = wcomb + i; }
    else if (i < 81920) { src = wv + (i - 16384); dst = wcomb + i; }
    else { src = wt + (i - 81920); dst = wtb + (i - 81920); }
    const float4 f = *reinterpret_cast<const float4*>(src);
    ushort4 u;
    u.x = bf16_rne(f.x); u.y = bf16_rne(f.y);
    u.z = bf16_rne(f.z); u.w = bf16_rne(f.w);
    *reinterpret_cast<ushort4*>(dst) = u;
}

// MFMA projection: one 1024-thread block per 64-n tile; 16 waves = 4 n-strips
// x 4 o-quarters (5 ot each). x staged once per block.
__global__ __launch_bounds__(1024, 4) void proj_kernel(
        const float* __restrict__ x, const unsigned short* __restrict__ wcomb,
        const float* __restrict__ bv, unsigned short* __restrict__ qkT,
        unsigned short* __restrict__ v) {
    __shared__ unsigned short xs[2][64][40];
    const int b = blockIdx.y;
    const int n0 = blockIdx.x * 64;
    const int tid = threadIdx.x;
    const int wave = tid >> 6, lane = tid & 63;
    const int ws = wave & 3, oq = wave >> 2;
    const int quad = lane >> 4, l15 = lane & 15;
    const int ca = tid >> 6, na = tid & 63;
    const int cb = (tid + 1024) >> 6, nb2 = (tid + 1024) & 63;
    f32x4 acc[5];
#pragma unroll
    for (int ot = 0; ot < 5; ++ot) acc[ot] = (f32x4){0.f, 0.f, 0.f, 0.f};
    xs[0][na][ca] = bf16_rne(x[((size_t)b * C_ + ca) * N_ + n0 + na]);
    xs[0][nb2][cb] = bf16_rne(x[((size_t)b * C_ + cb) * N_ + n0 + nb2]);
    __syncthreads();
    for (int ch = 0; ch < 8; ++ch) {
        const int buf = ch & 1;
        float la = 0.f, lb = 0.f;
        if (ch < 7) {
            la = x[((size_t)b * C_ + (ch + 1) * 32 + ca) * N_ + n0 + na];
            lb = x[((size_t)b * C_ + (ch + 1) * 32 + cb) * N_ + n0 + nb2];
        }
        const bf16x8 a = *reinterpret_cast<const bf16x8*>(&xs[buf][ws * 16 + l15][quad * 8]);
#pragma unroll
        for (int ot = 0; ot < 5; ++ot) {
            const int gro = oq * 5 + ot;
            const bf16x8 wb = *reinterpret_cast<const bf16x8*>(
                wcomb + (size_t)(gro * 16 + l15) * C_ + ch * 32 + quad * 8);
            acc[ot] = __builtin_amdgcn_mfma_f32_16x16x32_bf16(a, wb, acc[ot], 0, 0, 0);
        }
        if (ch < 7) {
            xs[buf ^ 1][na][ca] = bf16_rne(la);
            xs[buf ^ 1][nb2][cb] = bf16_rne(lb);
        }
        __syncthreads();
    }
    const int n = n0 + ws * 16 + quad * 4;
#pragma unroll
    for (int ot = 0; ot < 5; ++ot) {
        const int gro = oq * 5 + ot;
        if (gro < 4) {
            const int o = gro * 16 + l15;
#pragma unroll
            for (int r = 0; r < 4; ++r)
                qkT[((size_t)b * N_ + n + r) * C4_ + o] = bf16_rne(acc[ot][r]);
        } else {
            const int c = (gro - 4) * 16 + l15;
            const float bb = bv[c];
            ushort4 u;
            u.x = bf16_rne(acc[ot][0] + bb);
            u.y = bf16_rne(acc[ot][1] + bb);
            u.z = bf16_rne(acc[ot][2] + bb);
            u.w = bf16_rne(acc[ot][3] + bb);
            *reinterpret_cast<ushort4*>(&v[((size_t)b * C_ + c) * N_ + n]) = u;
        }
    }
}

// rowsuminv[b,n] = 1/sum_m exp(e[n,m]). DMA-staged (triple buffer, counted
// vmcnt, 1 barrier/iter, both-sides XOR swizzle) -- recipe verified in final
// v4. 16 waves = 4 n-strips x 4 m-subtiles; batch -> XCD-pair swizzle.
__global__ __launch_bounds__(1024, 4) void rowsum_kernel(
        const unsigned short* __restrict__ qkT, float* __restrict__ rowsuminv) {
    __shared__ unsigned short kt[3][64][64];     // 24 KB triple buffer (DMA)
    __shared__ float red[4][4][16];
    const int gid = blockIdx.x;
    const int xcd = gid & 7;
    const int b = xcd >> 1;
    const int n0 = ((((unsigned)gid >> 3) << 1) | (xcd & 1)) * 64;
    const int tid = threadIdx.x;
    const int wave = tid >> 6, lane = tid & 63;
    const int ws = wave & 3, sg = wave >> 2;
    const int quad = lane >> 4, l15 = lane & 15;
    const unsigned short* qb = qkT + (size_t)b * N_ * C4_;
    // DMA geometry (waves 0-7): lane l -> tile row wave*8 + (l>>3); source col
    // pre-swizzled so LDS[row][cs] = global[row][cs ^ ((row&7)*8)].
    const int rowA = lane >> 3;
    const int swc = ((lane & 7) ^ rowA) * 8;
    const int w8 = wave * 8;
    const int r7 = l15 & 7;
    const int c0s = (quad * 8) ^ (r7 << 3);
    const int c1s = (32 + quad * 8) ^ (r7 << 3);
    const unsigned short* qrow = qb + (size_t)(n0 + ws * 16 + l15) * C4_;
    const bf16x8 a0 = *reinterpret_cast<const bf16x8*>(qrow + quad * 8);
    const bf16x8 a1 = *reinterpret_cast<const bf16x8*>(qrow + 32 + quad * 8);
    asm volatile("s_waitcnt vmcnt(0)" ::: "memory");  // only DMAs counted below
#define RS_STAGE(sidx, bufS)                                                  \
    if (wave < 8) g2l16(qb + (size_t)((sidx) * 64 + w8 + rowA) * C4_ + swc,   \
                        &kt[bufS][w8][0]);
    RS_STAGE(0, 0);
    RS_STAGE(1, 1);
    if (wave < 8) asm volatile("s_waitcnt vmcnt(1)" ::: "memory");
    __builtin_amdgcn_s_barrier();
    float cs[4] = {};
    int bufR = 0;
#pragma unroll 1
    for (int mt = 0; mt < 64; ++mt) {
        if (mt <= 61) {
            int bufS = bufR + 2; if (bufS >= 3) bufS -= 3;
            RS_STAGE(mt + 2, bufS);
        }
        const bf16x8 kb0 = *reinterpret_cast<const bf16x8*>(&kt[bufR][sg * 16 + l15][c0s]);
        const bf16x8 kb1 = *reinterpret_cast<const bf16x8*>(&kt[bufR][sg * 16 + l15][c1s]);
        __builtin_amdgcn_s_setprio(1);
        f32x4 z = {0.f, 0.f, 0.f, 0.f};
        z = __builtin_amdgcn_mfma_f32_16x16x32_bf16(a0, kb0, z, 0, 0, 0);
        const f32x4 e = __builtin_amdgcn_mfma_f32_16x16x32_bf16(a1, kb1, z, 0, 0, 0);
        __builtin_amdgcn_s_setprio(0);
        cs[0] += __expf(e[0]); cs[1] += __expf(e[1]);
        cs[2] += __expf(e[2]); cs[3] += __expf(e[3]);
        asm volatile("s_waitcnt lgkmcnt(0)" ::: "memory");
        if (wave < 8) {
            if (mt <= 61)      asm volatile("s_waitcnt vmcnt(1)" ::: "memory");
            else if (mt == 62) asm volatile("s_waitcnt vmcnt(0)" ::: "memory");
        }
        __builtin_amdgcn_s_barrier();
        ++bufR; if (bufR >= 3) bufR = 0;
    }
#undef RS_STAGE
#pragma unroll
    for (int r = 0; r < 4; ++r) {
#pragma unroll
        for (int k = 1; k <= 8; k <<= 1) cs[r] += __shfl_xor(cs[r], k, 64);
        if (l15 == 0) red[sg][ws][quad * 4 + r] = cs[r];
    }
    __syncthreads();
    if (tid < 64) {
        const int ws2 = tid >> 4, row = tid & 15;
        const float sum = red[0][ws2][row] + red[1][ws2][row] +
                          red[2][ws2][row] + red[3][ws2][row];
        rowsuminv[(size_t)b * N_ + n0 + ws2 * 16 + row] = 1.0f / sum;
    }
}

// colsuminv[b,m] = 1/(1e-9 + sum_n exp(e[n,m])*rowsuminv[n]). Same DMA recipe:
// q-tiles staged (triple buffer, counted vmcnt, swizzle); kb in regs.
__global__ __launch_bounds__(1024, 4) void colsum_kernel(
        const unsigned short* __restrict__ qkT, const float* __restrict__ rowsuminv,
        float* __restrict__ colsuminv) {
    __shared__ float rl[N_];                     // 16 KB
    __shared__ unsigned short qt[3][64][64];     // 24 KB triple buffer (DMA)
    __shared__ float red[4][4][16];
    const int gid = blockIdx.x;
    const int xcd = gid & 7;
    const int b = xcd >> 1;
    const int m0 = ((((unsigned)gid >> 3) << 1) | (xcd & 1)) * 64;
    const int tid = threadIdx.x;
    const int wave = tid >> 6, lane = tid & 63;
    const int mw = wave & 3, ng = wave >> 2;
    const int quad = lane >> 4, l15 = lane & 15;
    const unsigned short* qb = qkT + (size_t)b * N_ * C4_;
    const int rowA = lane >> 3;
    const int swc = ((lane & 7) ^ rowA) * 8;
    const int w8 = wave * 8;
    const int r7 = l15 & 7;
    const int c0s = (quad * 8) ^ (r7 << 3);
    const int c1s = (32 + quad * 8) ^ (r7 << 3);
    for (int i = tid; i < N_; i += 1024) rl[i] = rowsuminv[(size_t)b * N_ + i];
    const unsigned short* krow = qb + (size_t)(m0 + mw * 16 + l15) * C4_;
    const bf16x8 kb0 = *reinterpret_cast<const bf16x8*>(krow + quad * 8);
    const bf16x8 kb1 = *reinterpret_cast<const bf16x8*>(krow + 32 + quad * 8);
    asm volatile("s_waitcnt vmcnt(0)" ::: "memory");  // only DMAs counted below
#define CS_STAGE(sidx, bufS)                                                  \
    if (wave < 8) g2l16(qb + (size_t)((sidx) * 64 + w8 + rowA) * C4_ + swc,   \
                        &qt[bufS][w8][0]);
    CS_STAGE(0, 0);
    CS_STAGE(1, 1);
    if (wave < 8) asm volatile("s_waitcnt vmcnt(1)" ::: "memory");
    asm volatile("s_waitcnt lgkmcnt(0)" ::: "memory");  // rl writes done
    __builtin_amdgcn_s_barrier();
    float cs = 0.f;
    int bufR = 0;
#pragma unroll 1
    for (int nt = 0; nt < 64; ++nt) {
        if (nt <= 61) {
            int bufS = bufR + 2; if (bufS >= 3) bufS -= 3;
            CS_STAGE(nt + 2, bufS);
        }
        const bf16x8 a0 = *reinterpret_cast<const bf16x8*>(&qt[bufR][ng * 16 + l15][c0s]);
        const bf16x8 a1 = *reinterpret_cast<const bf16x8*>(&qt[bufR][ng * 16 + l15][c1s]);
        __builtin_amdgcn_s_setprio(1);
        f32x4 z = {0.f, 0.f, 0.f, 0.f};
        z = __builtin_amdgcn_mfma_f32_16x16x32_bf16(a0, kb0, z, 0, 0, 0);
        const f32x4 e = __builtin_amdgcn_mfma_f32_16x16x32_bf16(a1, kb1, z, 0, 0, 0);
        __builtin_amdgcn_s_setprio(0);
        const int nb = nt * 64 + ng * 16 + quad * 4;
#pragma unroll
        for (int r = 0; r < 4; ++r) cs += __expf(e[r]) * rl[nb + r];
        asm volatile("s_waitcnt lgkmcnt(0)" ::: "memory");
        if (wave < 8) {
            if (nt <= 61)      asm volatile("s_waitcnt vmcnt(1)" ::: "memory");
            else if (nt == 62) asm volatile("s_waitcnt vmcnt(0)" ::: "memory");
        }
        __builtin_amdgcn_s_barrier();
        ++bufR; if (bufR >= 3) bufR = 0;
    }
#undef CS_STAGE
    cs += __shfl_xor(cs, 16, 64);
    cs += __shfl_xor(cs, 32, 64);
    if (quad == 0) red[ng][mw][l15] = cs;
    __syncthreads();
    if (tid < 64) {
        const int mw2 = tid >> 4, l = tid & 15;
        const float sum = red[0][mw2][l] + red[1][mw2][l] +
                          red[2][mw2][l] + red[3][mw2][l];
        colsuminv[(size_t)b * N_ + m0 + mw2 * 16 + l] = 1.0f / (1e-9f + sum);
    }
}

// Final v4 (+setprio, +explicit prologue drain): global_load_lds DMA staging,
// triple-buffered vt/kt, counted vmcnt (never 0 in steady state), 2 barriers
// per iter, both-sides XOR swizzle. 16 waves = 4 n-strips (ws) x 4 roles (g).
__global__ __launch_bounds__(1024, 4) void final_kernel(
        const float* __restrict__ x, const unsigned short* __restrict__ qkT,
        const unsigned short* __restrict__ v, const unsigned short* __restrict__ wtb,
        const float* __restrict__ rowsuminv, const float* __restrict__ colsuminv,
        const float* __restrict__ bt, const float* __restrict__ gamma,
        const float* __restrict__ beta, const float* __restrict__ rmean,
        const float* __restrict__ rvar, float* __restrict__ out) {
    __shared__ union {
        struct {
            unsigned short vt[3][256][64];                              // 96 KB
            unsigned short kt[3][64][64];                               // 24 KB
        } s;
        unsigned short dsm[64][268];                                    // 33.5 KB
    } u;
    __shared__ unsigned short p_sh[4][16][68];                          //  8.5 KB
    __shared__ float ci[N_];                                            // 16 KB
    const int gid = blockIdx.x;
    const int xcd = gid & 7;
    const int b = xcd >> 1;                       // batch -> XCD pair (L2 fit)
    const int n0 = ((((unsigned)gid >> 3) << 1) | (xcd & 1)) * 64;
    const int tid = threadIdx.x;
    const int wave = tid >> 6, lane = tid & 63;
    const int ws = wave & 3, g = wave >> 2;
    const int quad = lane >> 4, l15 = lane & 15;
    const unsigned short* qb = qkT + (size_t)b * N_ * C4_;
    const unsigned short* vbg = v + (size_t)b * C_ * N_;
    const int rowA = lane >> 3;                  // 0..7  (== row&7 of dest row)
    const int swc = ((lane & 7) ^ rowA) * 8;     // swizzled source col (shorts)
    const int w8 = wave * 8;
    const int r7 = l15 & 7;
    const int c0s = (quad * 8) ^ (r7 << 3);
    const int c1s = (32 + quad * 8) ^ (r7 << 3);
    const unsigned short* qrow = qb + (size_t)(n0 + ws * 16 + l15) * C4_;
    const bf16x8 q0 = *reinterpret_cast<const bf16x8*>(qrow + quad * 8);
    const bf16x8 q1 = *reinterpret_cast<const bf16x8*>(qrow + 32 + quad * 8);
    const float rli = rowsuminv[(size_t)b * N_ + n0 + ws * 16 + l15];
    {
        const float4 c4 = *reinterpret_cast<const float4*>(colsuminv + (size_t)b * N_ + tid * 4);
        *reinterpret_cast<float4*>(&ci[tid * 4]) = c4;
    }
    asm volatile("s_waitcnt vmcnt(0)" ::: "memory");  // only DMAs counted below
#define STAGE_TILE(sidx, bufS)                                                          \
    do {                                                                                \
        g2l16(vbg + (size_t)(w8 + rowA) * N_ + (sidx) * 64 + swc,                       \
              &u.s.vt[bufS][w8][0]);                                                    \
        g2l16(vbg + (size_t)(w8 + 128 + rowA) * N_ + (sidx) * 64 + swc,                 \
              &u.s.vt[bufS][w8 + 128][0]);                                              \
        if (wave < 8)                                                                   \
            g2l16(qb + (size_t)((sidx) * 64 + w8 + rowA) * C4_ + swc,                   \
                  &u.s.kt[bufS][w8][0]);                                                \
    } while (0)
    STAGE_TILE(0, 0);
    STAGE_TILE(1, 1);
    if (wave < 8) asm volatile("s_waitcnt vmcnt(3)" ::: "memory");
    else          asm volatile("s_waitcnt vmcnt(2)" ::: "memory");
    asm volatile("s_waitcnt lgkmcnt(0)" ::: "memory");
    __builtin_amdgcn_s_barrier();
    f32x4 acc[4];
#pragma unroll
    for (int j = 0; j < 4; ++j) acc[j] = (f32x4){0.f, 0.f, 0.f, 0.f};
    int bufR = 0;
#pragma unroll 1
    for (int t = 0; t < 64; ++t) {
        // issue stage(t+2) into the buffer no one reads this iteration
        if (t <= 61) {
            int bufS = bufR + 2; if (bufS >= 3) bufS -= 3;
            STAGE_TILE(t + 2, bufS);
        }
        // B: energy for (ws strip, g m-subtile): swapped mfma(K,Q).
        // lane holds e[n=l15][m = t*64 + g*16 + quad*4 + r]
        {
            const unsigned short(*ktb)[64] = u.s.kt[bufR];
            const bf16x8 ka0 = *reinterpret_cast<const bf16x8*>(&ktb[g * 16 + l15][c0s]);
            const bf16x8 ka1 = *reinterpret_cast<const bf16x8*>(&ktb[g * 16 + l15][c1s]);
            __builtin_amdgcn_s_setprio(1);
            f32x4 z = {0.f, 0.f, 0.f, 0.f};
            z = __builtin_amdgcn_mfma_f32_16x16x32_bf16(ka0, q0, z, 0, 0, 0);
            z = __builtin_amdgcn_mfma_f32_16x16x32_bf16(ka1, q1, z, 0, 0, 0);
            __builtin_amdgcn_s_setprio(0);
            const float4 civ = *reinterpret_cast<const float4*>(&ci[t * 64 + g * 16 + quad * 4]);
            ushort4 pk;
            pk.x = bf16_rne(__expf(z[0]) * rli * civ.x);
            pk.y = bf16_rne(__expf(z[1]) * rli * civ.y);
            pk.z = bf16_rne(__expf(z[2]) * rli * civ.z);
            pk.w = bf16_rne(__expf(z[3]) * rli * civ.w);
            *reinterpret_cast<ushort4*>(&p_sh[ws][l15][g * 16 + quad * 4]) = pk;
        }
        // C: p ready -- LDS fence + raw barrier (DMA stays in flight)
        asm volatile("s_waitcnt lgkmcnt(0)" ::: "memory");
        __builtin_amdgcn_s_barrier();
        // D: PV for (ws strip, g channel-quarter) over this m-tile
        {
            const bf16x8 pa0 = *reinterpret_cast<const bf16x8*>(&p_sh[ws][l15][quad * 8]);
            const bf16x8 pa1 = *reinterpret_cast<const bf16x8*>(&p_sh[ws][l15][32 + quad * 8]);
            const unsigned short(*vtb)[64] = u.s.vt[bufR];
            __builtin_amdgcn_s_setprio(1);
#pragma unroll
            for (int j = 0; j < 4; ++j) {
                const int vr = (g * 4 + j) * 16 + l15;
                const bf16x8 vb0 = *reinterpret_cast<const bf16x8*>(&vtb[vr][c0s]);
                const bf16x8 vb1 = *reinterpret_cast<const bf16x8*>(&vtb[vr][c1s]);
                acc[j] = __builtin_amdgcn_mfma_f32_16x16x32_bf16(pa0, vb0, acc[j], 0, 0, 0);
                acc[j] = __builtin_amdgcn_mfma_f32_16x16x32_bf16(pa1, vb1, acc[j], 0, 0, 0);
            }
            __builtin_amdgcn_s_setprio(0);
        }
        // F: own LDS reads drained; stage(t+1) landed (counted wait, never 0
        // in steady state -- stage(t+2) remains in flight); release bufR.
        asm volatile("s_waitcnt lgkmcnt(0)" ::: "memory");
        if (t <= 61) {
            if (wave < 8) asm volatile("s_waitcnt vmcnt(3)" ::: "memory");
            else          asm volatile("s_waitcnt vmcnt(2)" ::: "memory");
        } else {
            asm volatile("s_waitcnt vmcnt(0)" ::: "memory");
        }
        __builtin_amdgcn_s_barrier();
        ++bufR; if (bufR >= 3) bufR = 0;
    }
#undef STAGE_TILE
    // dsm = x - x_r (bf16); acc[j][r] = x_r[n=ws*16+quad*4+r][c=(g*4+j)*16+l15]
#pragma unroll
    for (int j = 0; j < 4; ++j) {
        const int c = (g * 4 + j) * 16 + l15;
        const float4 xv = *reinterpret_cast<const float4*>(
            &x[((size_t)b * C_ + c) * N_ + n0 + ws * 16 + quad * 4]);
        const float xvr[4] = {xv.x, xv.y, xv.z, xv.w};
#pragma unroll
        for (int r = 0; r < 4; ++r)
            u.dsm[ws * 16 + quad * 4 + r][c] = bf16_rne(xvr[r] - acc[j][r]);
    }
    __syncthreads();
    // wt GEMM: 4 strips x 4 o-quarters
    bf16x8 da[8];
#pragma unroll
    for (int k = 0; k < 8; ++k)
        da[k] = *reinterpret_cast<const bf16x8*>(&u.dsm[ws * 16 + l15][k * 32 + quad * 8]);
    f32x4 tacc[4];
#pragma unroll
    for (int j = 0; j < 4; ++j) tacc[j] = (f32x4){0.f, 0.f, 0.f, 0.f};
#pragma unroll
    for (int j = 0; j < 4; ++j) {
        const int ot = g * 4 + j;
#pragma unroll
        for (int k = 0; k < 8; ++k) {
            const bf16x8 wb = *reinterpret_cast<const bf16x8*>(
                wtb + (size_t)(ot * 16 + l15) * C_ + k * 32 + quad * 8);
            tacc[j] = __builtin_amdgcn_mfma_f32_16x16x32_bf16(da[k], wb, tacc[j], 0, 0, 0);
        }
    }
#pragma unroll
    for (int j = 0; j < 4; ++j) {
        const int o = (g * 4 + j) * 16 + l15;
        const float gg = gamma[o] * rsqrtf(rvar[o] + 1e-5f);
        const float mn = rmean[o], bbet = beta[o], bo = bt[o];
        const size_t oi = ((size_t)b * C_ + o) * N_ + n0 + ws * 16 + quad * 4;
        const float4 xo = *reinterpret_cast<const float4*>(&x[oi]);
        float4 res;
        res.x = xo.x + fmaxf((tacc[j][0] + bo - mn) * gg + bbet, 0.f);
        res.y = xo.y + fmaxf((tacc[j][1] + bo - mn) * gg + bbet, 0.f);
        res.z = xo.z + fmaxf((tacc[j][2] + bo - mn) * gg + bbet, 0.f);
        res.w = xo.w + fmaxf((tacc[j][3] + bo - mn) * gg + bbet, 0.f);
        *reinterpret_cast<float4*>(&out[oi]) = res;
    }
}

}  // namespace

extern "C" void kernel_launch(void* const* d_in, const int* in_sizes, int n_in,
                              void* d_out, int out_size, void* d_ws, size_t ws_size,
                              hipStream_t stream) {
    const float* x = (const float*)d_in[0];
    const float* wq = (const float*)d_in[1];
    const float* wv = (const float*)d_in[2];
    const float* bv = (const float*)d_in[3];
    const float* wt = (const float*)d_in[4];
    const float* bt = (const float*)d_in[5];
    const float* gamma = (const float*)d_in[6];
    const float* beta = (const float*)d_in[7];
    const float* rmean = (const float*)d_in[8];
    const float* rvar = (const float*)d_in[9];
    float* out = (float*)d_out;

    char* base = (char*)d_ws;
    unsigned short* qkT = (unsigned short*)base;                        // 2 MB
    unsigned short* vw = (unsigned short*)(base + (2u << 20));          // 8 MB
    unsigned short* wtb = (unsigned short*)(base + (10u << 20));        // 128 KB
    unsigned short* wcomb = (unsigned short*)(base + (10u << 20) + (128u << 10));
    float* rowsuminv = (float*)(base + (10u << 20) + (288u << 10));     // 64 KB
    float* colsuminv = (float*)(base + (10u << 20) + (352u << 10));     // 64 KB

    cvt_kernel<<<dim3(144), dim3(256), 0, stream>>>(wq, wv, wt, wcomb, wtb);
    proj_kernel<<<dim3(N_ / 64, B_), dim3(1024), 0, stream>>>(x, wcomb, bv, qkT, vw);
    rowsum_kernel<<<dim3(N_ / 64 * B_), dim3(1024), 0, stream>>>(qkT, rowsuminv);
    colsum_kernel<<<dim3(N_ / 64 * B_), dim3(1024), 0, stream>>>(qkT, rowsuminv, colsuminv);
    final_kernel<<<dim3(N_ / 64 * B_), dim3(1024), 0, stream>>>(
        x, qkT, vw, wtb, rowsuminv, colsuminv, bt, gamma, beta, rmean, rvar, out);
}

// Round 6
// 257.250 us; speedup vs baseline: 2.1829x; 1.0108x over previous
//
#include <hip/hip_runtime.h>
#include <math.h>

namespace {

constexpr int B_ = 4;
constexpr int C_ = 256;
constexpr int C4_ = 64;
constexpr int N_ = 4096;

typedef __attribute__((ext_vector_type(8))) short bf16x8;
typedef __attribute__((ext_vector_type(4))) float f32x4;
typedef __attribute__((ext_vector_type(16))) float f32x16;

__device__ __forceinline__ unsigned short bf16_rne(float f) {
    unsigned u = __float_as_uint(f);
    u += 0x7fffu + ((u >> 16) & 1u);
    return (unsigned short)(u >> 16);
}

// Async global->LDS DMA, 16B per lane. LDS dest = wave-uniform base + lane*16.
__device__ __forceinline__ void g2l16(const unsigned short* g, unsigned short* l) {
    __builtin_amdgcn_global_load_lds(
        (const __attribute__((address_space(1))) unsigned int*)g,
        (__attribute__((address_space(3))) unsigned int*)l, 16, 0, 0);
}

// Convert wq||wv -> wcomb bf16 [320,256], wt -> wtb bf16 [256,256].
__global__ __launch_bounds__(256) void cvt_kernel(
        const float* __restrict__ wq, const float* __restrict__ wv,
        const float* __restrict__ wt, unsigned short* __restrict__ wcomb,
        unsigned short* __restrict__ wtb) {
    const int i = (blockIdx.x * 256 + threadIdx.x) * 4;
    const float* src;
    unsigned short* dst;
    if (i < 16384) { src = wq + i; dst = wcomb + i; }
    else if (i < 81920) { src = wv + (i - 16384); dst = wcomb + i; }
    else { src = wt + (i - 81920); dst = wtb + (i - 81920); }
    const float4 f = *reinterpret_cast<const float4*>(src);
    ushort4 u;
    u.x = bf16_rne(f.x); u.y = bf16_rne(f.y);
    u.z = bf16_rne(f.z); u.w = bf16_rne(f.w);
    *reinterpret_cast<ushort4*>(dst) = u;
}

// MFMA projection: one 1024-thread block per 64-n tile; 16 waves = 4 n-strips
// x 4 o-quarters (5 ot each). x staged once per block.
__global__ __launch_bounds__(1024, 4) void proj_kernel(
        const float* __restrict__ x, const unsigned short* __restrict__ wcomb,
        const float* __restrict__ bv, unsigned short* __restrict__ qkT,
        unsigned short* __restrict__ v) {
    __shared__ unsigned short xs[2][64][40];
    const int b = blockIdx.y;
    const int n0 = blockIdx.x * 64;
    const int tid = threadIdx.x;
    const int wave = tid >> 6, lane = tid & 63;
    const int ws = wave & 3, oq = wave >> 2;
    const int quad = lane >> 4, l15 = lane & 15;
    const int ca = tid >> 6, na = tid & 63;
    const int cb = (tid + 1024) >> 6, nb2 = (tid + 1024) & 63;
    f32x4 acc[5];
#pragma unroll
    for (int ot = 0; ot < 5; ++ot) acc[ot] = (f32x4){0.f, 0.f, 0.f, 0.f};
    xs[0][na][ca] = bf16_rne(x[((size_t)b * C_ + ca) * N_ + n0 + na]);
    xs[0][nb2][cb] = bf16_rne(x[((size_t)b * C_ + cb) * N_ + n0 + nb2]);
    __syncthreads();
    for (int ch = 0; ch < 8; ++ch) {
        const int buf = ch & 1;
        float la = 0.f, lb = 0.f;
        if (ch < 7) {
            la = x[((size_t)b * C_ + (ch + 1) * 32 + ca) * N_ + n0 + na];
            lb = x[((size_t)b * C_ + (ch + 1) * 32 + cb) * N_ + n0 + nb2];
        }
        const bf16x8 a = *reinterpret_cast<const bf16x8*>(&xs[buf][ws * 16 + l15][quad * 8]);
#pragma unroll
        for (int ot = 0; ot < 5; ++ot) {
            const int gro = oq * 5 + ot;
            const bf16x8 wb = *reinterpret_cast<const bf16x8*>(
                wcomb + (size_t)(gro * 16 + l15) * C_ + ch * 32 + quad * 8);
            acc[ot] = __builtin_amdgcn_mfma_f32_16x16x32_bf16(a, wb, acc[ot], 0, 0, 0);
        }
        if (ch < 7) {
            xs[buf ^ 1][na][ca] = bf16_rne(la);
            xs[buf ^ 1][nb2][cb] = bf16_rne(lb);
        }
        __syncthreads();
    }
    const int n = n0 + ws * 16 + quad * 4;
#pragma unroll
    for (int ot = 0; ot < 5; ++ot) {
        const int gro = oq * 5 + ot;
        if (gro < 4) {
            const int o = gro * 16 + l15;
#pragma unroll
            for (int r = 0; r < 4; ++r)
                qkT[((size_t)b * N_ + n + r) * C4_ + o] = bf16_rne(acc[ot][r]);
        } else {
            const int c = (gro - 4) * 16 + l15;
            const float bb = bv[c];
            ushort4 u;
            u.x = bf16_rne(acc[ot][0] + bb);
            u.y = bf16_rne(acc[ot][1] + bb);
            u.z = bf16_rne(acc[ot][2] + bb);
            u.w = bf16_rne(acc[ot][3] + bb);
            *reinterpret_cast<ushort4*>(&v[((size_t)b * C_ + c) * N_ + n]) = u;
        }
    }
}

// rowsuminv[b,n] = 1/sum_m exp(e[n,m]). 32x32x16 MFMA, 256-m scan tiles,
// 16 iterations, 1 barrier/iter. q A-frags in regs; k-tiles DMA-staged
// (triple buffer, counted vmcnt, both-sides XOR swizzle -- verified recipe).
// 16 waves = 2 n-subtiles (nt) x 8 m-subtiles (ms).
__global__ __launch_bounds__(1024, 4) void rowsum_kernel(
        const unsigned short* __restrict__ qkT, float* __restrict__ rowsuminv) {
    __shared__ unsigned short kt[3][256][64];    // 96 KB triple buffer (DMA)
    __shared__ float red[2][8][2][16];           // 2 KB
    const int gid = blockIdx.x;
    const int xcd = gid & 7;
    const int b = xcd >> 1;
    const int n0 = ((((unsigned)gid >> 3) << 1) | (xcd & 1)) * 64;
    const int tid = threadIdx.x;
    const int wave = tid >> 6, lane = tid & 63;
    const int nt = wave >> 3, ms = wave & 7;
    const int l31 = lane & 31, h = lane >> 5;
    const unsigned short* qb = qkT + (size_t)b * N_ * C4_;
    // DMA: wave stages 16 rows (2 x 8-row 1KB chunks); source col pre-swizzled.
    const int rowA = lane >> 3;
    const int swc = ((lane & 7) ^ rowA) * 8;
    const int w16 = wave * 16;
    const int r7 = l31 & 7;
    // A-frags (q): rows n0 + nt*32 + l31, k-octet j*16 + h*8  (prologue gather)
    const unsigned short* qrow = qb + (size_t)(n0 + nt * 32 + l31) * C4_ + h * 8;
    bf16x8 qa[4];
#pragma unroll
    for (int j = 0; j < 4; ++j)
        qa[j] = *reinterpret_cast<const bf16x8*>(qrow + j * 16);
    asm volatile("s_waitcnt vmcnt(0)" ::: "memory");  // only DMAs counted below
#define RS_STAGE(sidx, bufS)                                                  \
    do {                                                                      \
        g2l16(qb + (size_t)((sidx) * 256 + w16 + rowA) * C4_ + swc,           \
              &kt[bufS][w16][0]);                                             \
        g2l16(qb + (size_t)((sidx) * 256 + w16 + 8 + rowA) * C4_ + swc,       \
              &kt[bufS][w16 + 8][0]);                                         \
    } while (0)
    RS_STAGE(0, 0);
    RS_STAGE(1, 1);
    asm volatile("s_waitcnt vmcnt(2)" ::: "memory");
    __builtin_amdgcn_s_barrier();
    f32x16 acc = (f32x16){0.f, 0.f, 0.f, 0.f, 0.f, 0.f, 0.f, 0.f,
                          0.f, 0.f, 0.f, 0.f, 0.f, 0.f, 0.f, 0.f};
    int bufR = 0;
#pragma unroll 1
    for (int t = 0; t < 16; ++t) {
        if (t <= 13) {
            int bufS = bufR + 2; if (bufS >= 3) bufS -= 3;
            RS_STAGE(t + 2, bufS);
        }
        // e tile: D[row = n-local (reg&3)+8*(reg>>2)+4*h][col = m-local l31]
        f32x16 z = (f32x16){0.f, 0.f, 0.f, 0.f, 0.f, 0.f, 0.f, 0.f,
                            0.f, 0.f, 0.f, 0.f, 0.f, 0.f, 0.f, 0.f};
        __builtin_amdgcn_s_setprio(1);
#pragma unroll
        for (int j = 0; j < 4; ++j) {
            const bf16x8 kb = *reinterpret_cast<const bf16x8*>(
                &kt[bufR][ms * 32 + l31][(j * 16 + h * 8) ^ (r7 << 3)]);
            z = __builtin_amdgcn_mfma_f32_32x32x16_bf16(qa[j], kb, z, 0, 0, 0);
        }
        __builtin_amdgcn_s_setprio(0);
#pragma unroll
        for (int r = 0; r < 16; ++r) acc[r] += __expf(z[r]);
        asm volatile("s_waitcnt lgkmcnt(0)" ::: "memory");
        if (t <= 13)      asm volatile("s_waitcnt vmcnt(2)" ::: "memory");
        else if (t == 14) asm volatile("s_waitcnt vmcnt(0)" ::: "memory");
        __builtin_amdgcn_s_barrier();
        ++bufR; if (bufR >= 3) bufR = 0;
    }
#undef RS_STAGE
    // reduce over m: 32-lane xor groups (col = l31), then over 8 ms waves
#pragma unroll
    for (int r = 0; r < 16; ++r) {
        float s = acc[r];
#pragma unroll
        for (int k = 1; k <= 16; k <<= 1) s += __shfl_xor(s, k, 64);
        if (l31 == 0) red[nt][ms][h][r] = s;
    }
    __syncthreads();
    if (tid < 64) {
        const int v = tid & 31, nt2 = tid >> 5;
        const int reg = (v & 3) | ((v >> 3) << 2);
        const int hh = (v >> 2) & 1;
        float sum = 0.f;
#pragma unroll
        for (int m = 0; m < 8; ++m) sum += red[nt2][m][hh][reg];
        rowsuminv[(size_t)b * N_ + n0 + nt2 * 32 + v] = 1.0f / sum;
    }
}

// colsuminv[b,m] = 1/(1e-9 + sum_n exp(e[n,m])*rowsuminv[n]). 32x32x16,
// 256-n scan tiles, 16 iters, 1 barrier/iter. k B-frags in regs; q-tiles
// DMA-staged. 16 waves = 2 m-subtiles (ms2) x 8 n-subtiles (ns).
__global__ __launch_bounds__(1024, 4) void colsum_kernel(
        const unsigned short* __restrict__ qkT, const float* __restrict__ rowsuminv,
        float* __restrict__ colsuminv) {
    __shared__ float rl[N_];                     // 16 KB
    __shared__ unsigned short qt[3][256][64];    // 96 KB triple buffer (DMA)
    __shared__ float red2[8][2][32];             // 2 KB
    const int gid = blockIdx.x;
    const int xcd = gid & 7;
    const int b = xcd >> 1;
    const int m0 = ((((unsigned)gid >> 3) << 1) | (xcd & 1)) * 64;
    const int tid = threadIdx.x;
    const int wave = tid >> 6, lane = tid & 63;
    const int ms2 = wave >> 3, ns = wave & 7;
    const int l31 = lane & 31, h = lane >> 5;
    const unsigned short* qb = qkT + (size_t)b * N_ * C4_;
    const int rowA = lane >> 3;
    const int swc = ((lane & 7) ^ rowA) * 8;
    const int w16 = wave * 16;
    const int r7 = l31 & 7;
    for (int i = tid; i < N_; i += 1024) rl[i] = rowsuminv[(size_t)b * N_ + i];
    // B-frags (k): rows m0 + ms2*32 + l31, k-octet j*16 + h*8 (prologue gather)
    const unsigned short* krow = qb + (size_t)(m0 + ms2 * 32 + l31) * C4_ + h * 8;
    bf16x8 kbf[4];
#pragma unroll
    for (int j = 0; j < 4; ++j)
        kbf[j] = *reinterpret_cast<const bf16x8*>(krow + j * 16);
    asm volatile("s_waitcnt vmcnt(0)" ::: "memory");  // only DMAs counted below
#define CS_STAGE(sidx, bufS)                                                  \
    do {                                                                      \
        g2l16(qb + (size_t)((sidx) * 256 + w16 + rowA) * C4_ + swc,           \
              &qt[bufS][w16][0]);                                             \
        g2l16(qb + (size_t)((sidx) * 256 + w16 + 8 + rowA) * C4_ + swc,       \
              &qt[bufS][w16 + 8][0]);                                         \
    } while (0)
    CS_STAGE(0, 0);
    CS_STAGE(1, 1);
    asm volatile("s_waitcnt vmcnt(2)" ::: "memory");
    asm volatile("s_waitcnt lgkmcnt(0)" ::: "memory");  // rl writes done
    __builtin_amdgcn_s_barrier();
    float csa = 0.f;
    int bufR = 0;
#pragma unroll 1
    for (int t = 0; t < 16; ++t) {
        if (t <= 13) {
            int bufS = bufR + 2; if (bufS >= 3) bufS -= 3;
            CS_STAGE(t + 2, bufS);
        }
        // e tile: D[row = n-local][col = m = m0 + ms2*32 + l31]
        f32x16 z = (f32x16){0.f, 0.f, 0.f, 0.f, 0.f, 0.f, 0.f, 0.f,
                            0.f, 0.f, 0.f, 0.f, 0.f, 0.f, 0.f, 0.f};
        __builtin_amdgcn_s_setprio(1);
#pragma unroll
        for (int j = 0; j < 4; ++j) {
            const bf16x8 qa = *reinterpret_cast<const bf16x8*>(
                &qt[bufR][ns * 32 + l31][(j * 16 + h * 8) ^ (r7 << 3)]);
            z = __builtin_amdgcn_mfma_f32_32x32x16_bf16(qa, kbf[j], z, 0, 0, 0);
        }
        __builtin_amdgcn_s_setprio(0);
        const int nb = t * 256 + ns * 32 + 4 * h;
#pragma unroll
        for (int r = 0; r < 16; ++r)
            csa += __expf(z[r]) * rl[nb + (r & 3) + 8 * (r >> 2)];
        asm volatile("s_waitcnt lgkmcnt(0)" ::: "memory");
        if (t <= 13)      asm volatile("s_waitcnt vmcnt(2)" ::: "memory");
        else if (t == 14) asm volatile("s_waitcnt vmcnt(0)" ::: "memory");
        __builtin_amdgcn_s_barrier();
        ++bufR; if (bufR >= 3) bufR = 0;
    }
#undef CS_STAGE
    csa += __shfl_xor(csa, 32, 64);              // combine n-halves (same m)
    if (h == 0) red2[ns][ms2][l31] = csa;
    __syncthreads();
    if (tid < 64) {
        const int ml = tid & 31, mg = tid >> 5;
        float sum = 0.f;
#pragma unroll
        for (int n = 0; n < 8; ++n) sum += red2[n][mg][ml];
        colsuminv[(size_t)b * N_ + m0 + mg * 32 + ml] = 1.0f / (1e-9f + sum);
    }
}

// Final v4 (+setprio): global_load_lds DMA staging, triple-buffered vt/kt,
// counted vmcnt (never 0 in steady state), 2 barriers/iter, both-sides XOR
// swizzle. 16 waves = 4 n-strips (ws) x 4 roles (g).
__global__ __launch_bounds__(1024, 4) void final_kernel(
        const float* __restrict__ x, const unsigned short* __restrict__ qkT,
        const unsigned short* __restrict__ v, const unsigned short* __restrict__ wtb,
        const float* __restrict__ rowsuminv, const float* __restrict__ colsuminv,
        const float* __restrict__ bt, const float* __restrict__ gamma,
        const float* __restrict__ beta, const float* __restrict__ rmean,
        const float* __restrict__ rvar, float* __restrict__ out) {
    __shared__ union {
        struct {
            unsigned short vt[3][256][64];                              // 96 KB
            unsigned short kt[3][64][64];                               // 24 KB
        } s;
        unsigned short dsm[64][268];                                    // 33.5 KB
    } u;
    __shared__ unsigned short p_sh[4][16][68];                          //  8.5 KB
    __shared__ float ci[N_];                                            // 16 KB
    const int gid = blockIdx.x;
    const int xcd = gid & 7;
    const int b = xcd >> 1;                       // batch -> XCD pair (L2 fit)
    const int n0 = ((((unsigned)gid >> 3) << 1) | (xcd & 1)) * 64;
    const int tid = threadIdx.x;
    const int wave = tid >> 6, lane = tid & 63;
    const int ws = wave & 3, g = wave >> 2;
    const int quad = lane >> 4, l15 = lane & 15;
    const unsigned short* qb = qkT + (size_t)b * N_ * C4_;
    const unsigned short* vbg = v + (size_t)b * C_ * N_;
    const int rowA = lane >> 3;                  // 0..7  (== row&7 of dest row)
    const int swc = ((lane & 7) ^ rowA) * 8;     // swizzled source col (shorts)
    const int w8 = wave * 8;
    const int r7 = l15 & 7;
    const int c0s = (quad * 8) ^ (r7 << 3);
    const int c1s = (32 + quad * 8) ^ (r7 << 3);
    const unsigned short* qrow = qb + (size_t)(n0 + ws * 16 + l15) * C4_;
    const bf16x8 q0 = *reinterpret_cast<const bf16x8*>(qrow + quad * 8);
    const bf16x8 q1 = *reinterpret_cast<const bf16x8*>(qrow + 32 + quad * 8);
    const float rli = rowsuminv[(size_t)b * N_ + n0 + ws * 16 + l15];
    {
        const float4 c4 = *reinterpret_cast<const float4*>(colsuminv + (size_t)b * N_ + tid * 4);
        *reinterpret_cast<float4*>(&ci[tid * 4]) = c4;
    }
    asm volatile("s_waitcnt vmcnt(0)" ::: "memory");  // only DMAs counted below
#define STAGE_TILE(sidx, bufS)                                                          \
    do {                                                                                \
        g2l16(vbg + (size_t)(w8 + rowA) * N_ + (sidx) * 64 + swc,                       \
              &u.s.vt[bufS][w8][0]);                                                    \
        g2l16(vbg + (size_t)(w8 + 128 + rowA) * N_ + (sidx) * 64 + swc,                 \
              &u.s.vt[bufS][w8 + 128][0]);                                              \
        if (wave < 8)                                                                   \
            g2l16(qb + (size_t)((sidx) * 64 + w8 + rowA) * C4_ + swc,                   \
                  &u.s.kt[bufS][w8][0]);                                                \
    } while (0)
    STAGE_TILE(0, 0);
    STAGE_TILE(1, 1);
    if (wave < 8) asm volatile("s_waitcnt vmcnt(3)" ::: "memory");
    else          asm volatile("s_waitcnt vmcnt(2)" ::: "memory");
    asm volatile("s_waitcnt lgkmcnt(0)" ::: "memory");
    __builtin_amdgcn_s_barrier();
    f32x4 acc[4];
#pragma unroll
    for (int j = 0; j < 4; ++j) acc[j] = (f32x4){0.f, 0.f, 0.f, 0.f};
    int bufR = 0;
#pragma unroll 1
    for (int t = 0; t < 64; ++t) {
        // issue stage(t+2) into the buffer no one reads this iteration
        if (t <= 61) {
            int bufS = bufR + 2; if (bufS >= 3) bufS -= 3;
            STAGE_TILE(t + 2, bufS);
        }
        // B: energy for (ws strip, g m-subtile): swapped mfma(K,Q).
        // lane holds e[n=l15][m = t*64 + g*16 + quad*4 + r]
        {
            const unsigned short(*ktb)[64] = u.s.kt[bufR];
            const bf16x8 ka0 = *reinterpret_cast<const bf16x8*>(&ktb[g * 16 + l15][c0s]);
            const bf16x8 ka1 = *reinterpret_cast<const bf16x8*>(&ktb[g * 16 + l15][c1s]);
            __builtin_amdgcn_s_setprio(1);
            f32x4 z = {0.f, 0.f, 0.f, 0.f};
            z = __builtin_amdgcn_mfma_f32_16x16x32_bf16(ka0, q0, z, 0, 0, 0);
            z = __builtin_amdgcn_mfma_f32_16x16x32_bf16(ka1, q1, z, 0, 0, 0);
            __builtin_amdgcn_s_setprio(0);
            const float4 civ = *reinterpret_cast<const float4*>(&ci[t * 64 + g * 16 + quad * 4]);
            ushort4 pk;
            pk.x = bf16_rne(__expf(z[0]) * rli * civ.x);
            pk.y = bf16_rne(__expf(z[1]) * rli * civ.y);
            pk.z = bf16_rne(__expf(z[2]) * rli * civ.z);
            pk.w = bf16_rne(__expf(z[3]) * rli * civ.w);
            *reinterpret_cast<ushort4*>(&p_sh[ws][l15][g * 16 + quad * 4]) = pk;
        }
        // C: p ready -- LDS fence + raw barrier (DMA stays in flight)
        asm volatile("s_waitcnt lgkmcnt(0)" ::: "memory");
        __builtin_amdgcn_s_barrier();
        // D: PV for (ws strip, g channel-quarter) over this m-tile
        {
            const bf16x8 pa0 = *reinterpret_cast<const bf16x8*>(&p_sh[ws][l15][quad * 8]);
            const bf16x8 pa1 = *reinterpret_cast<const bf16x8*>(&p_sh[ws][l15][32 + quad * 8]);
            const unsigned short(*vtb)[64] = u.s.vt[bufR];
            __builtin_amdgcn_s_setprio(1);
#pragma unroll
            for (int j = 0; j < 4; ++j) {
                const int vr = (g * 4 + j) * 16 + l15;
                const bf16x8 vb0 = *reinterpret_cast<const bf16x8*>(&vtb[vr][c0s]);
                const bf16x8 vb1 = *reinterpret_cast<const bf16x8*>(&vtb[vr][c1s]);
                acc[j] = __builtin_amdgcn_mfma_f32_16x16x32_bf16(pa0, vb0, acc[j], 0, 0, 0);
                acc[j] = __builtin_amdgcn_mfma_f32_16x16x32_bf16(pa1, vb1, acc[j], 0, 0, 0);
            }
            __builtin_amdgcn_s_setprio(0);
        }
        // F: own LDS reads drained; stage(t+1) landed (counted wait, never 0
        // in steady state -- stage(t+2) remains in flight); release bufR.
        asm volatile("s_waitcnt lgkmcnt(0)" ::: "memory");
        if (t <= 61) {
            if (wave < 8) asm volatile("s_waitcnt vmcnt(3)" ::: "memory");
            else          asm volatile("s_waitcnt vmcnt(2)" ::: "memory");
        } else {
            asm volatile("s_waitcnt vmcnt(0)" ::: "memory");
        }
        __builtin_amdgcn_s_barrier();
        ++bufR; if (bufR >= 3) bufR = 0;
    }
#undef STAGE_TILE
    // dsm = x - x_r (bf16); acc[j][r] = x_r[n=ws*16+quad*4+r][c=(g*4+j)*16+l15]
#pragma unroll
    for (int j = 0; j < 4; ++j) {
        const int c = (g * 4 + j) * 16 + l15;
        const float4 xv = *reinterpret_cast<const float4*>(
            &x[((size_t)b * C_ + c) * N_ + n0 + ws * 16 + quad * 4]);
        const float xvr[4] = {xv.x, xv.y, xv.z, xv.w};
#pragma unroll
        for (int r = 0; r < 4; ++r)
            u.dsm[ws * 16 + quad * 4 + r][c] = bf16_rne(xvr[r] - acc[j][r]);
    }
    __syncthreads();
    // wt GEMM: 4 strips x 4 o-quarters
    bf16x8 da[8];
#pragma unroll
    for (int k = 0; k < 8; ++k)
        da[k] = *reinterpret_cast<const bf16x8*>(&u.dsm[ws * 16 + l15][k * 32 + quad * 8]);
    f32x4 tacc[4];
#pragma unroll
    for (int j = 0; j < 4; ++j) tacc[j] = (f32x4){0.f, 0.f, 0.f, 0.f};
#pragma unroll
    for (int j = 0; j < 4; ++j) {
        const int ot = g * 4 + j;
#pragma unroll
        for (int k = 0; k < 8; ++k) {
            const bf16x8 wb = *reinterpret_cast<const bf16x8*>(
                wtb + (size_t)(ot * 16 + l15) * C_ + k * 32 + quad * 8);
            tacc[j] = __builtin_amdgcn_mfma_f32_16x16x32_bf16(da[k], wb, tacc[j], 0, 0, 0);
        }
    }
#pragma unroll
    for (int j = 0; j < 4; ++j) {
        const int o = (g * 4 + j) * 16 + l15;
        const float gg = gamma[o] * rsqrtf(rvar[o] + 1e-5f);
        const float mn = rmean[o], bbet = beta[o], bo = bt[o];
        const size_t oi = ((size_t)b * C_ + o) * N_ + n0 + ws * 16 + quad * 4;
        const float4 xo = *reinterpret_cast<const float4*>(&x[oi]);
        float4 res;
        res.x = xo.x + fmaxf((tacc[j][0] + bo - mn) * gg + bbet, 0.f);
        res.y = xo.y + fmaxf((tacc[j][1] + bo - mn) * gg + bbet, 0.f);
        res.z = xo.z + fmaxf((tacc[j][2] + bo - mn) * gg + bbet, 0.f);
        res.w = xo.w + fmaxf((tacc[j][3] + bo - mn) * gg + bbet, 0.f);
        *reinterpret_cast<float4*>(&out[oi]) = res;
    }
}

}  // namespace

extern "C" void kernel_launch(void* const* d_in, const int* in_sizes, int n_in,
                              void* d_out, int out_size, void* d_ws, size_t ws_size,
                              hipStream_t stream) {
    const float* x = (const float*)d_in[0];
    const float* wq = (const float*)d_in[1];
    const float* wv = (const float*)d_in[2];
    const float* bv = (const float*)d_in[3];
    const float* wt = (const float*)d_in[4];
    const float* bt = (const float*)d_in[5];
    const float* gamma = (const float*)d_in[6];
    const float* beta = (const float*)d_in[7];
    const float* rmean = (const float*)d_in[8];
    const float* rvar = (const float*)d_in[9];
    float* out = (float*)d_out;

    char* base = (char*)d_ws;
    unsigned short* qkT = (unsigned short*)base;                        // 2 MB
    unsigned short* vw = (unsigned short*)(base + (2u << 20));          // 8 MB
    unsigned short* wtb = (unsigned short*)(base + (10u << 20));        // 128 KB
    unsigned short* wcomb = (unsigned short*)(base + (10u << 20) + (128u << 10));
    float* rowsuminv = (float*)(base + (10u << 20) + (288u << 10));     // 64 KB
    float* colsuminv = (float*)(base + (10u << 20) + (352u << 10));     // 64 KB

    cvt_kernel<<<dim3(144), dim3(256), 0, stream>>>(wq, wv, wt, wcomb, wtb);
    proj_kernel<<<dim3(N_ / 64, B_), dim3(1024), 0, stream>>>(x, wcomb, bv, qkT, vw);
    rowsum_kernel<<<dim3(N_ / 64 * B_), dim3(1024), 0, stream>>>(qkT, rowsuminv);
    colsum_kernel<<<dim3(N_ / 64 * B_), dim3(1024), 0, stream>>>(qkT, rowsuminv, colsuminv);
    final_kernel<<<dim3(N_ / 64 * B_), dim3(1024), 0, stream>>>(
        x, qkT, vw, wtb, rowsuminv, colsuminv, bt, gamma, beta, rmean, rvar, out);
}

// Round 7
// 250.132 us; speedup vs baseline: 2.2450x; 1.0285x over previous
//
#include <hip/hip_runtime.h>
#include <math.h>

namespace {

constexpr int B_ = 4;
constexpr int C_ = 256;
constexpr int C4_ = 64;
constexpr int N_ = 4096;

typedef __attribute__((ext_vector_type(8))) short bf16x8;
typedef __attribute__((ext_vector_type(4))) float f32x4;
typedef __attribute__((ext_vector_type(16))) float f32x16;

__device__ __forceinline__ unsigned short bf16_rne(float f) {
    unsigned u = __float_as_uint(f);
    u += 0x7fffu + ((u >> 16) & 1u);
    return (unsigned short)(u >> 16);
}

// Async global->LDS DMA, 16B per lane. LDS dest = wave-uniform base + lane*16.
__device__ __forceinline__ void g2l16(const unsigned short* g, unsigned short* l) {
    __builtin_amdgcn_global_load_lds(
        (const __attribute__((address_space(1))) unsigned int*)g,
        (__attribute__((address_space(3))) unsigned int*)l, 16, 0, 0);
}

// Convert wq||wv -> wfrag (per-lane MFMA B-fragment order, so proj's loads are
// lane-coalesced 1KB blocks): wfrag[((gro*8+ch)*64 + quad*16 + l15)*8 + e]
//   = wcomb[gro*16+l15][ch*32+quad*8+e].   wt -> wtb [256][256] row-major.
__global__ __launch_bounds__(256) void cvt_kernel(
        const float* __restrict__ wq, const float* __restrict__ wv,
        const float* __restrict__ wt, unsigned short* __restrict__ wfrag,
        unsigned short* __restrict__ wtb) {
    const int i = (blockIdx.x * 256 + threadIdx.x) * 4;
    const float* src;
    unsigned short* dst;
    if (i < 81920) {
        src = (i < 16384) ? (wq + i) : (wv + (i - 16384));
        const int o = i >> 8, c = i & 255;
        const int gro = o >> 4, l15 = o & 15;
        const int ch = c >> 5, quad = (c >> 3) & 3, e = c & 7;
        dst = wfrag + (((gro * 8 + ch) * 64 + quad * 16 + l15) * 8 + e);
    } else {
        src = wt + (i - 81920);
        dst = wtb + (i - 81920);
    }
    const float4 f = *reinterpret_cast<const float4*>(src);
    ushort4 u;
    u.x = bf16_rne(f.x); u.y = bf16_rne(f.y);
    u.z = bf16_rne(f.z); u.w = bf16_rne(f.w);
    *reinterpret_cast<ushort4*>(dst) = u;
}

// MFMA projection: one 1024-thread block per 64-n tile; 16 waves = 4 n-strips
// x 4 o-quarters (5 ot each). x staged once per block. B-frags from wfrag are
// lane-coalesced (no gathers); xs pad 42 -> conflict-free staging writes.
__global__ __launch_bounds__(1024, 4) void proj_kernel(
        const float* __restrict__ x, const unsigned short* __restrict__ wfragb,
        const float* __restrict__ bv, unsigned short* __restrict__ qkT,
        unsigned short* __restrict__ v) {
    __shared__ unsigned short xs[2][64][42];
    const int b = blockIdx.y;
    const int n0 = blockIdx.x * 64;
    const int tid = threadIdx.x;
    const int wave = tid >> 6, lane = tid & 63;
    const int ws = wave & 3, oq = wave >> 2;
    const int quad = lane >> 4, l15 = lane & 15;
    const int ca = tid >> 6, na = tid & 63;
    const int cb = (tid + 1024) >> 6, nb2 = (tid + 1024) & 63;
    f32x4 acc[5];
#pragma unroll
    for (int ot = 0; ot < 5; ++ot) acc[ot] = (f32x4){0.f, 0.f, 0.f, 0.f};
    xs[0][na][ca] = bf16_rne(x[((size_t)b * C_ + ca) * N_ + n0 + na]);
    xs[0][nb2][cb] = bf16_rne(x[((size_t)b * C_ + cb) * N_ + n0 + nb2]);
    __syncthreads();
    for (int ch = 0; ch < 8; ++ch) {
        const int buf = ch & 1;
        float la = 0.f, lb = 0.f;
        if (ch < 7) {
            la = x[((size_t)b * C_ + (ch + 1) * 32 + ca) * N_ + n0 + na];
            lb = x[((size_t)b * C_ + (ch + 1) * 32 + cb) * N_ + n0 + nb2];
        }
        const bf16x8 a = *reinterpret_cast<const bf16x8*>(&xs[buf][ws * 16 + l15][quad * 8]);
#pragma unroll
        for (int ot = 0; ot < 5; ++ot) {
            const int gro = oq * 5 + ot;
            const bf16x8 wb = *reinterpret_cast<const bf16x8*>(
                wfragb + (size_t)(((gro * 8 + ch) * 64 + lane) * 8));
            acc[ot] = __builtin_amdgcn_mfma_f32_16x16x32_bf16(a, wb, acc[ot], 0, 0, 0);
        }
        if (ch < 7) {
            xs[buf ^ 1][na][ca] = bf16_rne(la);
            xs[buf ^ 1][nb2][cb] = bf16_rne(lb);
        }
        __syncthreads();
    }
    const int n = n0 + ws * 16 + quad * 4;
#pragma unroll
    for (int ot = 0; ot < 5; ++ot) {
        const int gro = oq * 5 + ot;
        if (gro < 4) {
            const int o = gro * 16 + l15;
#pragma unroll
            for (int r = 0; r < 4; ++r)
                qkT[((size_t)b * N_ + n + r) * C4_ + o] = bf16_rne(acc[ot][r]);
        } else {
            const int c = (gro - 4) * 16 + l15;
            const float bb = bv[c];
            ushort4 u;
            u.x = bf16_rne(acc[ot][0] + bb);
            u.y = bf16_rne(acc[ot][1] + bb);
            u.z = bf16_rne(acc[ot][2] + bb);
            u.w = bf16_rne(acc[ot][3] + bb);
            *reinterpret_cast<ushort4*>(&v[((size_t)b * C_ + c) * N_ + n]) = u;
        }
    }
}

// rowsuminv[b,n] = 1/sum_m exp(e[n,m]). 32x32x16 MFMA, 256-m scan tiles,
// 16 iterations, 1 barrier/iter. q A-frags in regs; k-tiles DMA-staged
// (triple buffer, counted vmcnt, both-sides XOR swizzle -- verified recipe).
// 16 waves = 2 n-subtiles (nt) x 8 m-subtiles (ms).
__global__ __launch_bounds__(1024, 4) void rowsum_kernel(
        const unsigned short* __restrict__ qkT, float* __restrict__ rowsuminv) {
    __shared__ unsigned short kt[3][256][64];    // 96 KB triple buffer (DMA)
    __shared__ float red[2][8][2][16];           // 2 KB
    const int gid = blockIdx.x;
    const int xcd = gid & 7;
    const int b = xcd >> 1;
    const int n0 = ((((unsigned)gid >> 3) << 1) | (xcd & 1)) * 64;
    const int tid = threadIdx.x;
    const int wave = tid >> 6, lane = tid & 63;
    const int nt = wave >> 3, ms = wave & 7;
    const int l31 = lane & 31, h = lane >> 5;
    const unsigned short* qb = qkT + (size_t)b * N_ * C4_;
    // DMA: wave stages 16 rows (2 x 8-row 1KB chunks); source col pre-swizzled.
    const int rowA = lane >> 3;
    const int swc = ((lane & 7) ^ rowA) * 8;
    const int w16 = wave * 16;
    const int r7 = l31 & 7;
    // A-frags (q): rows n0 + nt*32 + l31, k-octet j*16 + h*8  (prologue gather)
    const unsigned short* qrow = qb + (size_t)(n0 + nt * 32 + l31) * C4_ + h * 8;
    bf16x8 qa[4];
#pragma unroll
    for (int j = 0; j < 4; ++j)
        qa[j] = *reinterpret_cast<const bf16x8*>(qrow + j * 16);
    asm volatile("s_waitcnt vmcnt(0)" ::: "memory");  // only DMAs counted below
#define RS_STAGE(sidx, bufS)                                                  \
    do {                                                                      \
        g2l16(qb + (size_t)((sidx) * 256 + w16 + rowA) * C4_ + swc,           \
              &kt[bufS][w16][0]);                                             \
        g2l16(qb + (size_t)((sidx) * 256 + w16 + 8 + rowA) * C4_ + swc,       \
              &kt[bufS][w16 + 8][0]);                                         \
    } while (0)
    RS_STAGE(0, 0);
    RS_STAGE(1, 1);
    asm volatile("s_waitcnt vmcnt(2)" ::: "memory");
    __builtin_amdgcn_s_barrier();
    f32x16 acc = (f32x16){0.f, 0.f, 0.f, 0.f, 0.f, 0.f, 0.f, 0.f,
                          0.f, 0.f, 0.f, 0.f, 0.f, 0.f, 0.f, 0.f};
    int bufR = 0;
#pragma unroll 1
    for (int t = 0; t < 16; ++t) {
        if (t <= 13) {
            int bufS = bufR + 2; if (bufS >= 3) bufS -= 3;
            RS_STAGE(t + 2, bufS);
        }
        // e tile: D[row = n-local (reg&3)+8*(reg>>2)+4*h][col = m-local l31]
        f32x16 z = (f32x16){0.f, 0.f, 0.f, 0.f, 0.f, 0.f, 0.f, 0.f,
                            0.f, 0.f, 0.f, 0.f, 0.f, 0.f, 0.f, 0.f};
        __builtin_amdgcn_s_setprio(1);
#pragma unroll
        for (int j = 0; j < 4; ++j) {
            const bf16x8 kb = *reinterpret_cast<const bf16x8*>(
                &kt[bufR][ms * 32 + l31][(j * 16 + h * 8) ^ (r7 << 3)]);
            z = __builtin_amdgcn_mfma_f32_32x32x16_bf16(qa[j], kb, z, 0, 0, 0);
        }
        __builtin_amdgcn_s_setprio(0);
#pragma unroll
        for (int r = 0; r < 16; ++r) acc[r] += __expf(z[r]);
        asm volatile("s_waitcnt lgkmcnt(0)" ::: "memory");
        if (t <= 13)      asm volatile("s_waitcnt vmcnt(2)" ::: "memory");
        else if (t == 14) asm volatile("s_waitcnt vmcnt(0)" ::: "memory");
        __builtin_amdgcn_s_barrier();
        ++bufR; if (bufR >= 3) bufR = 0;
    }
#undef RS_STAGE
    // reduce over m: 32-lane xor groups (col = l31), then over 8 ms waves
#pragma unroll
    for (int r = 0; r < 16; ++r) {
        float s = acc[r];
#pragma unroll
        for (int k = 1; k <= 16; k <<= 1) s += __shfl_xor(s, k, 64);
        if (l31 == 0) red[nt][ms][h][r] = s;
    }
    __syncthreads();
    if (tid < 64) {
        const int v = tid & 31, nt2 = tid >> 5;
        const int reg = (v & 3) | ((v >> 3) << 2);
        const int hh = (v >> 2) & 1;
        float sum = 0.f;
#pragma unroll
        for (int m = 0; m < 8; ++m) sum += red[nt2][m][hh][reg];
        rowsuminv[(size_t)b * N_ + n0 + nt2 * 32 + v] = 1.0f / sum;
    }
}

// colsuminv[b,m] = 1/(1e-9 + sum_n exp(e[n,m])*rowsuminv[n]). 32x32x16,
// 256-n scan tiles, 16 iters, 1 barrier/iter. k B-frags in regs; q-tiles
// DMA-staged. 16 waves = 2 m-subtiles (ms2) x 8 n-subtiles (ns).
__global__ __launch_bounds__(1024, 4) void colsum_kernel(
        const unsigned short* __restrict__ qkT, const float* __restrict__ rowsuminv,
        float* __restrict__ colsuminv) {
    __shared__ float rl[N_];                     // 16 KB
    __shared__ unsigned short qt[3][256][64];    // 96 KB triple buffer (DMA)
    __shared__ float red2[8][2][32];             // 2 KB
    const int gid = blockIdx.x;
    const int xcd = gid & 7;
    const int b = xcd >> 1;
    const int m0 = ((((unsigned)gid >> 3) << 1) | (xcd & 1)) * 64;
    const int tid = threadIdx.x;
    const int wave = tid >> 6, lane = tid & 63;
    const int ms2 = wave >> 3, ns = wave & 7;
    const int l31 = lane & 31, h = lane >> 5;
    const unsigned short* qb = qkT + (size_t)b * N_ * C4_;
    const int rowA = lane >> 3;
    const int swc = ((lane & 7) ^ rowA) * 8;
    const int w16 = wave * 16;
    const int r7 = l31 & 7;
    for (int i = tid; i < N_; i += 1024) rl[i] = rowsuminv[(size_t)b * N_ + i];
    // B-frags (k): rows m0 + ms2*32 + l31, k-octet j*16 + h*8 (prologue gather)
    const unsigned short* krow = qb + (size_t)(m0 + ms2 * 32 + l31) * C4_ + h * 8;
    bf16x8 kbf[4];
#pragma unroll
    for (int j = 0; j < 4; ++j)
        kbf[j] = *reinterpret_cast<const bf16x8*>(krow + j * 16);
    asm volatile("s_waitcnt vmcnt(0)" ::: "memory");  // only DMAs counted below
#define CS_STAGE(sidx, bufS)                                                  \
    do {                                                                      \
        g2l16(qb + (size_t)((sidx) * 256 + w16 + rowA) * C4_ + swc,           \
              &qt[bufS][w16][0]);                                             \
        g2l16(qb + (size_t)((sidx) * 256 + w16 + 8 + rowA) * C4_ + swc,       \
              &qt[bufS][w16 + 8][0]);                                         \
    } while (0)
    CS_STAGE(0, 0);
    CS_STAGE(1, 1);
    asm volatile("s_waitcnt vmcnt(2)" ::: "memory");
    asm volatile("s_waitcnt lgkmcnt(0)" ::: "memory");  // rl writes done
    __builtin_amdgcn_s_barrier();
    float csa = 0.f;
    int bufR = 0;
#pragma unroll 1
    for (int t = 0; t < 16; ++t) {
        if (t <= 13) {
            int bufS = bufR + 2; if (bufS >= 3) bufS -= 3;
            CS_STAGE(t + 2, bufS);
        }
        // e tile: D[row = n-local][col = m = m0 + ms2*32 + l31]
        f32x16 z = (f32x16){0.f, 0.f, 0.f, 0.f, 0.f, 0.f, 0.f, 0.f,
                            0.f, 0.f, 0.f, 0.f, 0.f, 0.f, 0.f, 0.f};
        __builtin_amdgcn_s_setprio(1);
#pragma unroll
        for (int j = 0; j < 4; ++j) {
            const bf16x8 qa = *reinterpret_cast<const bf16x8*>(
                &qt[bufR][ns * 32 + l31][(j * 16 + h * 8) ^ (r7 << 3)]);
            z = __builtin_amdgcn_mfma_f32_32x32x16_bf16(qa, kbf[j], z, 0, 0, 0);
        }
        __builtin_amdgcn_s_setprio(0);
        const int nb = t * 256 + ns * 32 + 4 * h;
#pragma unroll
        for (int r = 0; r < 16; ++r)
            csa += __expf(z[r]) * rl[nb + (r & 3) + 8 * (r >> 2)];
        asm volatile("s_waitcnt lgkmcnt(0)" ::: "memory");
        if (t <= 13)      asm volatile("s_waitcnt vmcnt(2)" ::: "memory");
        else if (t == 14) asm volatile("s_waitcnt vmcnt(0)" ::: "memory");
        __builtin_amdgcn_s_barrier();
        ++bufR; if (bufR >= 3) bufR = 0;
    }
#undef CS_STAGE
    csa += __shfl_xor(csa, 32, 64);              // combine n-halves (same m)
    if (h == 0) red2[ns][ms2][l31] = csa;
    __syncthreads();
    if (tid < 64) {
        const int ml = tid & 31, mg = tid >> 5;
        float sum = 0.f;
#pragma unroll
        for (int n = 0; n < 8; ++n) sum += red2[n][mg][ml];
        colsuminv[(size_t)b * N_ + m0 + mg * 32 + ml] = 1.0f / (1e-9f + sum);
    }
}

// Final v5: DMA staging + triple buffer + counted vmcnt (verified). Energy
// waves = 4 n-strips (ws) x 4 m-subtiles (g), unchanged. PV repartitioned to
// 2 n-halves (h2) x 8 c-slices (csl): per-wave LDS reads 12 -> 10 b128,
// block read traffic 192 -> 160 KB/iter. Accumulation order per output
// element unchanged (bit-identical result).
__global__ __launch_bounds__(1024, 4) void final_kernel(
        const float* __restrict__ x, const unsigned short* __restrict__ qkT,
        const unsigned short* __restrict__ v, const unsigned short* __restrict__ wtb,
        const float* __restrict__ rowsuminv, const float* __restrict__ colsuminv,
        const float* __restrict__ bt, const float* __restrict__ gamma,
        const float* __restrict__ beta, const float* __restrict__ rmean,
        const float* __restrict__ rvar, float* __restrict__ out) {
    __shared__ union {
        struct {
            unsigned short vt[3][256][64];                              // 96 KB
            unsigned short kt[3][64][64];                               // 24 KB
        } s;
        unsigned short dsm[64][268];                                    // 33.5 KB
    } u;
    __shared__ unsigned short p_sh[4][16][68];                          //  8.5 KB
    __shared__ float ci[N_];                                            // 16 KB
    const int gid = blockIdx.x;
    const int xcd = gid & 7;
    const int b = xcd >> 1;                       // batch -> XCD pair (L2 fit)
    const int n0 = ((((unsigned)gid >> 3) << 1) | (xcd & 1)) * 64;
    const int tid = threadIdx.x;
    const int wave = tid >> 6, lane = tid & 63;
    const int ws = wave & 3, g = wave >> 2;       // energy decomposition
    const int h2 = wave & 1, csl = wave >> 1;     // PV decomposition
    const int quad = lane >> 4, l15 = lane & 15;
    const unsigned short* qb = qkT + (size_t)b * N_ * C4_;
    const unsigned short* vbg = v + (size_t)b * C_ * N_;
    const int rowA = lane >> 3;                  // 0..7  (== row&7 of dest row)
    const int swc = ((lane & 7) ^ rowA) * 8;     // swizzled source col (shorts)
    const int w8 = wave * 8;
    const int r7 = l15 & 7;
    const int c0s = (quad * 8) ^ (r7 << 3);
    const int c1s = (32 + quad * 8) ^ (r7 << 3);
    const unsigned short* qrow = qb + (size_t)(n0 + ws * 16 + l15) * C4_;
    const bf16x8 q0 = *reinterpret_cast<const bf16x8*>(qrow + quad * 8);
    const bf16x8 q1 = *reinterpret_cast<const bf16x8*>(qrow + 32 + quad * 8);
    const float rli = rowsuminv[(size_t)b * N_ + n0 + ws * 16 + l15];
    {
        const float4 c4 = *reinterpret_cast<const float4*>(colsuminv + (size_t)b * N_ + tid * 4);
        *reinterpret_cast<float4*>(&ci[tid * 4]) = c4;
    }
    asm volatile("s_waitcnt vmcnt(0)" ::: "memory");  // only DMAs counted below
#define STAGE_TILE(sidx, bufS)                                                          \
    do {                                                                                \
        g2l16(vbg + (size_t)(w8 + rowA) * N_ + (sidx) * 64 + swc,                       \
              &u.s.vt[bufS][w8][0]);                                                    \
        g2l16(vbg + (size_t)(w8 + 128 + rowA) * N_ + (sidx) * 64 + swc,                 \
              &u.s.vt[bufS][w8 + 128][0]);                                              \
        if (wave < 8)                                                                   \
            g2l16(qb + (size_t)((sidx) * 64 + w8 + rowA) * C4_ + swc,                   \
                  &u.s.kt[bufS][w8][0]);                                                \
    } while (0)
    STAGE_TILE(0, 0);
    STAGE_TILE(1, 1);
    if (wave < 8) asm volatile("s_waitcnt vmcnt(3)" ::: "memory");
    else          asm volatile("s_waitcnt vmcnt(2)" ::: "memory");
    asm volatile("s_waitcnt lgkmcnt(0)" ::: "memory");
    __builtin_amdgcn_s_barrier();
    f32x4 acc[4];   // acc[ss*2+j] = x_r tile [n-strip h2*2+ss][c16 csl*2+j]
#pragma unroll
    for (int j = 0; j < 4; ++j) acc[j] = (f32x4){0.f, 0.f, 0.f, 0.f};
    int bufR = 0;
#pragma unroll 1
    for (int t = 0; t < 64; ++t) {
        // issue stage(t+2) into the buffer no one reads this iteration
        if (t <= 61) {
            int bufS = bufR + 2; if (bufS >= 3) bufS -= 3;
            STAGE_TILE(t + 2, bufS);
        }
        // B: energy for (ws strip, g m-subtile): swapped mfma(K,Q).
        // lane holds e[n=l15][m = t*64 + g*16 + quad*4 + r]
        {
            const unsigned short(*ktb)[64] = u.s.kt[bufR];
            const bf16x8 ka0 = *reinterpret_cast<const bf16x8*>(&ktb[g * 16 + l15][c0s]);
            const bf16x8 ka1 = *reinterpret_cast<const bf16x8*>(&ktb[g * 16 + l15][c1s]);
            __builtin_amdgcn_s_setprio(1);
            f32x4 z = {0.f, 0.f, 0.f, 0.f};
            z = __builtin_amdgcn_mfma_f32_16x16x32_bf16(ka0, q0, z, 0, 0, 0);
            z = __builtin_amdgcn_mfma_f32_16x16x32_bf16(ka1, q1, z, 0, 0, 0);
            __builtin_amdgcn_s_setprio(0);
            const float4 civ = *reinterpret_cast<const float4*>(&ci[t * 64 + g * 16 + quad * 4]);
            ushort4 pk;
            pk.x = bf16_rne(__expf(z[0]) * rli * civ.x);
            pk.y = bf16_rne(__expf(z[1]) * rli * civ.y);
            pk.z = bf16_rne(__expf(z[2]) * rli * civ.z);
            pk.w = bf16_rne(__expf(z[3]) * rli * civ.w);
            *reinterpret_cast<ushort4*>(&p_sh[ws][l15][g * 16 + quad * 4]) = pk;
        }
        // C: p ready -- LDS fence + raw barrier (DMA stays in flight)
        asm volatile("s_waitcnt lgkmcnt(0)" ::: "memory");
        __builtin_amdgcn_s_barrier();
        // D: PV for (h2 n-half, csl c-slice): 2 strips x 2 c16 x K=64
        {
            const unsigned short(*vtb)[64] = u.s.vt[bufR];
            bf16x8 pa[2][2], vb[2][2];
#pragma unroll
            for (int ss = 0; ss < 2; ++ss) {
                pa[ss][0] = *reinterpret_cast<const bf16x8*>(&p_sh[h2 * 2 + ss][l15][quad * 8]);
                pa[ss][1] = *reinterpret_cast<const bf16x8*>(&p_sh[h2 * 2 + ss][l15][32 + quad * 8]);
            }
#pragma unroll
            for (int j = 0; j < 2; ++j) {
                const int vr = csl * 32 + j * 16 + l15;
                vb[j][0] = *reinterpret_cast<const bf16x8*>(&vtb[vr][c0s]);
                vb[j][1] = *reinterpret_cast<const bf16x8*>(&vtb[vr][c1s]);
            }
            __builtin_amdgcn_s_setprio(1);
#pragma unroll
            for (int ss = 0; ss < 2; ++ss)
#pragma unroll
                for (int j = 0; j < 2; ++j) {
                    acc[ss * 2 + j] = __builtin_amdgcn_mfma_f32_16x16x32_bf16(
                        pa[ss][0], vb[j][0], acc[ss * 2 + j], 0, 0, 0);
                    acc[ss * 2 + j] = __builtin_amdgcn_mfma_f32_16x16x32_bf16(
                        pa[ss][1], vb[j][1], acc[ss * 2 + j], 0, 0, 0);
                }
            __builtin_amdgcn_s_setprio(0);
        }
        // F: own LDS reads drained; stage(t+1) landed (counted wait, never 0
        // in steady state -- stage(t+2) remains in flight); release bufR.
        asm volatile("s_waitcnt lgkmcnt(0)" ::: "memory");
        if (t <= 61) {
            if (wave < 8) asm volatile("s_waitcnt vmcnt(3)" ::: "memory");
            else          asm volatile("s_waitcnt vmcnt(2)" ::: "memory");
        } else {
            asm volatile("s_waitcnt vmcnt(0)" ::: "memory");
        }
        __builtin_amdgcn_s_barrier();
        ++bufR; if (bufR >= 3) bufR = 0;
    }
#undef STAGE_TILE
    // dsm = x - x_r (bf16); acc[ss*2+j][r] =
    //   x_r[n=(h2*2+ss)*16+quad*4+r][c=csl*32+j*16+l15]
#pragma unroll
    for (int ss = 0; ss < 2; ++ss)
#pragma unroll
    for (int j = 0; j < 2; ++j) {
        const int c = csl * 32 + j * 16 + l15;
        const int nn = (h2 * 2 + ss) * 16 + quad * 4;
        const float4 xv = *reinterpret_cast<const float4*>(
            &x[((size_t)b * C_ + c) * N_ + n0 + nn]);
        const float xvr[4] = {xv.x, xv.y, xv.z, xv.w};
#pragma unroll
        for (int r = 0; r < 4; ++r)
            u.dsm[nn + r][c] = bf16_rne(xvr[r] - acc[ss * 2 + j][r]);
    }
    __syncthreads();
    // wt GEMM: 4 strips x 4 o-quarters
    bf16x8 da[8];
#pragma unroll
    for (int k = 0; k < 8; ++k)
        da[k] = *reinterpret_cast<const bf16x8*>(&u.dsm[ws * 16 + l15][k * 32 + quad * 8]);
    f32x4 tacc[4];
#pragma unroll
    for (int j = 0; j < 4; ++j) tacc[j] = (f32x4){0.f, 0.f, 0.f, 0.f};
#pragma unroll
    for (int j = 0; j < 4; ++j) {
        const int ot = g * 4 + j;
#pragma unroll
        for (int k = 0; k < 8; ++k) {
            const bf16x8 wb = *reinterpret_cast<const bf16x8*>(
                wtb + (size_t)(ot * 16 + l15) * C_ + k * 32 + quad * 8);
            tacc[j] = __builtin_amdgcn_mfma_f32_16x16x32_bf16(da[k], wb, tacc[j], 0, 0, 0);
        }
    }
#pragma unroll
    for (int j = 0; j < 4; ++j) {
        const int o = (g * 4 + j) * 16 + l15;
        const float gg = gamma[o] * rsqrtf(rvar[o] + 1e-5f);
        const float mn = rmean[o], bbet = beta[o], bo = bt[o];
        const size_t oi = ((size_t)b * C_ + o) * N_ + n0 + ws * 16 + quad * 4;
        const float4 xo = *reinterpret_cast<const float4*>(&x[oi]);
        float4 res;
        res.x = xo.x + fmaxf((tacc[j][0] + bo - mn) * gg + bbet, 0.f);
        res.y = xo.y + fmaxf((tacc[j][1] + bo - mn) * gg + bbet, 0.f);
        res.z = xo.z + fmaxf((tacc[j][2] + bo - mn) * gg + bbet, 0.f);
        res.w = xo.w + fmaxf((tacc[j][3] + bo - mn) * gg + bbet, 0.f);
        *reinterpret_cast<float4*>(&out[oi]) = res;
    }
}

}  // namespace

extern "C" void kernel_launch(void* const* d_in, const int* in_sizes, int n_in,
                              void* d_out, int out_size, void* d_ws, size_t ws_size,
                              hipStream_t stream) {
    const float* x = (const float*)d_in[0];
    const float* wq = (const float*)d_in[1];
    const float* wv = (const float*)d_in[2];
    const float* bv = (const float*)d_in[3];
    const float* wt = (const float*)d_in[4];
    const float* bt = (const float*)d_in[5];
    const float* gamma = (const float*)d_in[6];
    const float* beta = (const float*)d_in[7];
    const float* rmean = (const float*)d_in[8];
    const float* rvar = (const float*)d_in[9];
    float* out = (float*)d_out;

    char* base = (char*)d_ws;
    unsigned short* qkT = (unsigned short*)base;                        // 2 MB
    unsigned short* vw = (unsigned short*)(base + (2u << 20));          // 8 MB
    unsigned short* wtb = (unsigned short*)(base + (10u << 20));        // 128 KB
    unsigned short* wfrag = (unsigned short*)(base + (10u << 20) + (128u << 10));
    float* rowsuminv = (float*)(base + (10u << 20) + (288u << 10));     // 64 KB
    float* colsuminv = (float*)(base + (10u << 20) + (352u << 10));     // 64 KB

    cvt_kernel<<<dim3(144), dim3(256), 0, stream>>>(wq, wv, wt, wfrag, wtb);
    proj_kernel<<<dim3(N_ / 64, B_), dim3(1024), 0, stream>>>(x, wfrag, bv, qkT, vw);
    rowsum_kernel<<<dim3(N_ / 64 * B_), dim3(1024), 0, stream>>>(qkT, rowsuminv);
    colsum_kernel<<<dim3(N_ / 64 * B_), dim3(1024), 0, stream>>>(qkT, rowsuminv, colsuminv);
    final_kernel<<<dim3(N_ / 64 * B_), dim3(1024), 0, stream>>>(
        x, qkT, vw, wtb, rowsuminv, colsuminv, bt, gamma, beta, rmean, rvar, out);
}

// Round 8
// 246.640 us; speedup vs baseline: 2.2768x; 1.0142x over previous
//
#include <hip/hip_runtime.h>
#include <math.h>

namespace {

constexpr int B_ = 4;
constexpr int C_ = 256;
constexpr int C4_ = 64;
constexpr int N_ = 4096;

typedef __attribute__((ext_vector_type(8))) short bf16x8;
typedef __attribute__((ext_vector_type(4))) float f32x4;
typedef __attribute__((ext_vector_type(16))) float f32x16;

__device__ __forceinline__ unsigned short bf16_rne(float f) {
    unsigned u = __float_as_uint(f);
    u += 0x7fffu + ((u >> 16) & 1u);
    return (unsigned short)(u >> 16);
}

// Async global->LDS DMA, 16B per lane. LDS dest = wave-uniform base + lane*16.
__device__ __forceinline__ void g2l16(const unsigned short* g, unsigned short* l) {
    __builtin_amdgcn_global_load_lds(
        (const __attribute__((address_space(1))) unsigned int*)g,
        (__attribute__((address_space(3))) unsigned int*)l, 16, 0, 0);
}

// Convert wq||wv -> wfrag (per-lane MFMA B-fragment order, so proj's loads are
// lane-coalesced 1KB blocks): wfrag[((gro*8+ch)*64 + quad*16 + l15)*8 + e]
//   = wcomb[gro*16+l15][ch*32+quad*8+e].   wt -> wtb [256][256] row-major.
__global__ __launch_bounds__(256) void cvt_kernel(
        const float* __restrict__ wq, const float* __restrict__ wv,
        const float* __restrict__ wt, unsigned short* __restrict__ wfrag,
        unsigned short* __restrict__ wtb) {
    const int i = (blockIdx.x * 256 + threadIdx.x) * 4;
    const float* src;
    unsigned short* dst;
    if (i < 81920) {
        src = (i < 16384) ? (wq + i) : (wv + (i - 16384));
        const int o = i >> 8, c = i & 255;
        const int gro = o >> 4, l15 = o & 15;
        const int ch = c >> 5, quad = (c >> 3) & 3, e = c & 7;
        dst = wfrag + (((gro * 8 + ch) * 64 + quad * 16 + l15) * 8 + e);
    } else {
        src = wt + (i - 81920);
        dst = wtb + (i - 81920);
    }
    const float4 f = *reinterpret_cast<const float4*>(src);
    ushort4 u;
    u.x = bf16_rne(f.x); u.y = bf16_rne(f.y);
    u.z = bf16_rne(f.z); u.w = bf16_rne(f.w);
    *reinterpret_cast<ushort4*>(dst) = u;
}

// MFMA projection: one 1024-thread block per 64-n tile; 16 waves = 4 n-strips
// x 4 o-quarters (5 ot each). x staged once per block. B-frags from wfrag are
// lane-coalesced (no gathers); xs pad 42 -> conflict-free staging writes.
__global__ __launch_bounds__(1024, 4) void proj_kernel(
        const float* __restrict__ x, const unsigned short* __restrict__ wfragb,
        const float* __restrict__ bv, unsigned short* __restrict__ qkT,
        unsigned short* __restrict__ v) {
    __shared__ unsigned short xs[2][64][42];
    const int b = blockIdx.y;
    const int n0 = blockIdx.x * 64;
    const int tid = threadIdx.x;
    const int wave = tid >> 6, lane = tid & 63;
    const int ws = wave & 3, oq = wave >> 2;
    const int quad = lane >> 4, l15 = lane & 15;
    const int ca = tid >> 6, na = tid & 63;
    const int cb = (tid + 1024) >> 6, nb2 = (tid + 1024) & 63;
    f32x4 acc[5];
#pragma unroll
    for (int ot = 0; ot < 5; ++ot) acc[ot] = (f32x4){0.f, 0.f, 0.f, 0.f};
    xs[0][na][ca] = bf16_rne(x[((size_t)b * C_ + ca) * N_ + n0 + na]);
    xs[0][nb2][cb] = bf16_rne(x[((size_t)b * C_ + cb) * N_ + n0 + nb2]);
    __syncthreads();
    for (int ch = 0; ch < 8; ++ch) {
        const int buf = ch & 1;
        float la = 0.f, lb = 0.f;
        if (ch < 7) {
            la = x[((size_t)b * C_ + (ch + 1) * 32 + ca) * N_ + n0 + na];
            lb = x[((size_t)b * C_ + (ch + 1) * 32 + cb) * N_ + n0 + nb2];
        }
        const bf16x8 a = *reinterpret_cast<const bf16x8*>(&xs[buf][ws * 16 + l15][quad * 8]);
#pragma unroll
        for (int ot = 0; ot < 5; ++ot) {
            const int gro = oq * 5 + ot;
            const bf16x8 wb = *reinterpret_cast<const bf16x8*>(
                wfragb + (size_t)(((gro * 8 + ch) * 64 + lane) * 8));
            acc[ot] = __builtin_amdgcn_mfma_f32_16x16x32_bf16(a, wb, acc[ot], 0, 0, 0);
        }
        if (ch < 7) {
            xs[buf ^ 1][na][ca] = bf16_rne(la);
            xs[buf ^ 1][nb2][cb] = bf16_rne(lb);
        }
        __syncthreads();
    }
    const int n = n0 + ws * 16 + quad * 4;
#pragma unroll
    for (int ot = 0; ot < 5; ++ot) {
        const int gro = oq * 5 + ot;
        if (gro < 4) {
            const int o = gro * 16 + l15;
#pragma unroll
            for (int r = 0; r < 4; ++r)
                qkT[((size_t)b * N_ + n + r) * C4_ + o] = bf16_rne(acc[ot][r]);
        } else {
            const int c = (gro - 4) * 16 + l15;
            const float bb = bv[c];
            ushort4 u;
            u.x = bf16_rne(acc[ot][0] + bb);
            u.y = bf16_rne(acc[ot][1] + bb);
            u.z = bf16_rne(acc[ot][2] + bb);
            u.w = bf16_rne(acc[ot][3] + bb);
            *reinterpret_cast<ushort4*>(&v[((size_t)b * C_ + c) * N_ + n]) = u;
        }
    }
}

// rowsuminv[b,n] = 1/sum_m exp(e[n,m]). 32x32x16 MFMA, 256-m scan tiles,
// 16 iterations, 1 barrier/iter. q A-frags in regs; k-tiles DMA-staged
// (triple buffer, counted vmcnt, both-sides XOR swizzle -- verified recipe).
// 16 waves = 2 n-subtiles (nt) x 8 m-subtiles (ms).
__global__ __launch_bounds__(1024, 4) void rowsum_kernel(
        const unsigned short* __restrict__ qkT, float* __restrict__ rowsuminv) {
    __shared__ unsigned short kt[3][256][64];    // 96 KB triple buffer (DMA)
    __shared__ float red[2][8][2][16];           // 2 KB
    const int gid = blockIdx.x;
    const int xcd = gid & 7;
    const int b = xcd >> 1;
    const int n0 = ((((unsigned)gid >> 3) << 1) | (xcd & 1)) * 64;
    const int tid = threadIdx.x;
    const int wave = tid >> 6, lane = tid & 63;
    const int nt = wave >> 3, ms = wave & 7;
    const int l31 = lane & 31, h = lane >> 5;
    const unsigned short* qb = qkT + (size_t)b * N_ * C4_;
    // DMA: wave stages 16 rows (2 x 8-row 1KB chunks); source col pre-swizzled.
    const int rowA = lane >> 3;
    const int swc = ((lane & 7) ^ rowA) * 8;
    const int w16 = wave * 16;
    const int r7 = l31 & 7;
    // A-frags (q): rows n0 + nt*32 + l31, k-octet j*16 + h*8  (prologue gather)
    const unsigned short* qrow = qb + (size_t)(n0 + nt * 32 + l31) * C4_ + h * 8;
    bf16x8 qa[4];
#pragma unroll
    for (int j = 0; j < 4; ++j)
        qa[j] = *reinterpret_cast<const bf16x8*>(qrow + j * 16);
    asm volatile("s_waitcnt vmcnt(0)" ::: "memory");  // only DMAs counted below
#define RS_STAGE(sidx, bufS)                                                  \
    do {                                                                      \
        g2l16(qb + (size_t)((sidx) * 256 + w16 + rowA) * C4_ + swc,           \
              &kt[bufS][w16][0]);                                             \
        g2l16(qb + (size_t)((sidx) * 256 + w16 + 8 + rowA) * C4_ + swc,       \
              &kt[bufS][w16 + 8][0]);                                         \
    } while (0)
    RS_STAGE(0, 0);
    RS_STAGE(1, 1);
    asm volatile("s_waitcnt vmcnt(2)" ::: "memory");
    __builtin_amdgcn_s_barrier();
    f32x16 acc = (f32x16){0.f, 0.f, 0.f, 0.f, 0.f, 0.f, 0.f, 0.f,
                          0.f, 0.f, 0.f, 0.f, 0.f, 0.f, 0.f, 0.f};
    int bufR = 0;
#pragma unroll 1
    for (int t = 0; t < 16; ++t) {
        if (t <= 13) {
            int bufS = bufR + 2; if (bufS >= 3) bufS -= 3;
            RS_STAGE(t + 2, bufS);
        }
        // e tile: D[row = n-local (reg&3)+8*(reg>>2)+4*h][col = m-local l31]
        f32x16 z = (f32x16){0.f, 0.f, 0.f, 0.f, 0.f, 0.f, 0.f, 0.f,
                            0.f, 0.f, 0.f, 0.f, 0.f, 0.f, 0.f, 0.f};
        __builtin_amdgcn_s_setprio(1);
#pragma unroll
        for (int j = 0; j < 4; ++j) {
            const bf16x8 kb = *reinterpret_cast<const bf16x8*>(
                &kt[bufR][ms * 32 + l31][(j * 16 + h * 8) ^ (r7 << 3)]);
            z = __builtin_amdgcn_mfma_f32_32x32x16_bf16(qa[j], kb, z, 0, 0, 0);
        }
        __builtin_amdgcn_s_setprio(0);
#pragma unroll
        for (int r = 0; r < 16; ++r) acc[r] += __expf(z[r]);
        asm volatile("s_waitcnt lgkmcnt(0)" ::: "memory");
        if (t <= 13)      asm volatile("s_waitcnt vmcnt(2)" ::: "memory");
        else if (t == 14) asm volatile("s_waitcnt vmcnt(0)" ::: "memory");
        __builtin_amdgcn_s_barrier();
        ++bufR; if (bufR >= 3) bufR = 0;
    }
#undef RS_STAGE
    // reduce over m: 32-lane xor groups (col = l31), then over 8 ms waves
#pragma unroll
    for (int r = 0; r < 16; ++r) {
        float s = acc[r];
#pragma unroll
        for (int k = 1; k <= 16; k <<= 1) s += __shfl_xor(s, k, 64);
        if (l31 == 0) red[nt][ms][h][r] = s;
    }
    __syncthreads();
    if (tid < 64) {
        const int v = tid & 31, nt2 = tid >> 5;
        const int reg = (v & 3) | ((v >> 3) << 2);
        const int hh = (v >> 2) & 1;
        float sum = 0.f;
#pragma unroll
        for (int m = 0; m < 8; ++m) sum += red[nt2][m][hh][reg];
        rowsuminv[(size_t)b * N_ + n0 + nt2 * 32 + v] = 1.0f / sum;
    }
}

// colsuminv[b,m] = 1/(1e-9 + sum_n exp(e[n,m])*rowsuminv[n]). 32x32x16,
// 256-n scan tiles, 16 iters, 1 barrier/iter. k B-frags in regs; q-tiles
// DMA-staged. 16 waves = 2 m-subtiles (ms2) x 8 n-subtiles (ns).
__global__ __launch_bounds__(1024, 4) void colsum_kernel(
        const unsigned short* __restrict__ qkT, const float* __restrict__ rowsuminv,
        float* __restrict__ colsuminv) {
    __shared__ float rl[N_];                     // 16 KB
    __shared__ unsigned short qt[3][256][64];    // 96 KB triple buffer (DMA)
    __shared__ float red2[8][2][32];             // 2 KB
    const int gid = blockIdx.x;
    const int xcd = gid & 7;
    const int b = xcd >> 1;
    const int m0 = ((((unsigned)gid >> 3) << 1) | (xcd & 1)) * 64;
    const int tid = threadIdx.x;
    const int wave = tid >> 6, lane = tid & 63;
    const int ms2 = wave >> 3, ns = wave & 7;
    const int l31 = lane & 31, h = lane >> 5;
    const unsigned short* qb = qkT + (size_t)b * N_ * C4_;
    const int rowA = lane >> 3;
    const int swc = ((lane & 7) ^ rowA) * 8;
    const int w16 = wave * 16;
    const int r7 = l31 & 7;
    for (int i = tid; i < N_; i += 1024) rl[i] = rowsuminv[(size_t)b * N_ + i];
    // B-frags (k): rows m0 + ms2*32 + l31, k-octet j*16 + h*8 (prologue gather)
    const unsigned short* krow = qb + (size_t)(m0 + ms2 * 32 + l31) * C4_ + h * 8;
    bf16x8 kbf[4];
#pragma unroll
    for (int j = 0; j < 4; ++j)
        kbf[j] = *reinterpret_cast<const bf16x8*>(krow + j * 16);
    asm volatile("s_waitcnt vmcnt(0)" ::: "memory");  // only DMAs counted below
#define CS_STAGE(sidx, bufS)                                                  \
    do {                                                                      \
        g2l16(qb + (size_t)((sidx) * 256 + w16 + rowA) * C4_ + swc,           \
              &qt[bufS][w16][0]);                                             \
        g2l16(qb + (size_t)((sidx) * 256 + w16 + 8 + rowA) * C4_ + swc,       \
              &qt[bufS][w16 + 8][0]);                                         \
    } while (0)
    CS_STAGE(0, 0);
    CS_STAGE(1, 1);
    asm volatile("s_waitcnt vmcnt(2)" ::: "memory");
    asm volatile("s_waitcnt lgkmcnt(0)" ::: "memory");  // rl writes done
    __builtin_amdgcn_s_barrier();
    float csa = 0.f;
    int bufR = 0;
#pragma unroll 1
    for (int t = 0; t < 16; ++t) {
        if (t <= 13) {
            int bufS = bufR + 2; if (bufS >= 3) bufS -= 3;
            CS_STAGE(t + 2, bufS);
        }
        // e tile: D[row = n-local][col = m = m0 + ms2*32 + l31]
        f32x16 z = (f32x16){0.f, 0.f, 0.f, 0.f, 0.f, 0.f, 0.f, 0.f,
                            0.f, 0.f, 0.f, 0.f, 0.f, 0.f, 0.f, 0.f};
        __builtin_amdgcn_s_setprio(1);
#pragma unroll
        for (int j = 0; j < 4; ++j) {
            const bf16x8 qa = *reinterpret_cast<const bf16x8*>(
                &qt[bufR][ns * 32 + l31][(j * 16 + h * 8) ^ (r7 << 3)]);
            z = __builtin_amdgcn_mfma_f32_32x32x16_bf16(qa, kbf[j], z, 0, 0, 0);
        }
        __builtin_amdgcn_s_setprio(0);
        const int nb = t * 256 + ns * 32 + 4 * h;
#pragma unroll
        for (int r = 0; r < 16; ++r)
            csa += __expf(z[r]) * rl[nb + (r & 3) + 8 * (r >> 2)];
        asm volatile("s_waitcnt lgkmcnt(0)" ::: "memory");
        if (t <= 13)      asm volatile("s_waitcnt vmcnt(2)" ::: "memory");
        else if (t == 14) asm volatile("s_waitcnt vmcnt(0)" ::: "memory");
        __builtin_amdgcn_s_barrier();
        ++bufR; if (bufR >= 3) bufR = 0;
    }
#undef CS_STAGE
    csa += __shfl_xor(csa, 32, 64);              // combine n-halves (same m)
    if (h == 0) red2[ns][ms2][l31] = csa;
    __syncthreads();
    if (tid < 64) {
        const int ml = tid & 31, mg = tid >> 5;
        float sum = 0.f;
#pragma unroll
        for (int n = 0; n < 8; ++n) sum += red2[n][mg][ml];
        colsuminv[(size_t)b * N_ + m0 + mg * 32 + ml] = 1.0f / (1e-9f + sum);
    }
}

// Final v6: fused-phase pipeline -- energy(t) and PV(t-1) run between the
// SAME barrier pair (p_sh double-buffered), ONE barrier per iteration.
// vt triple-buffered (stage dist 1), kt triple-buffered (dist 2), counted
// vmcnt identical to the verified v4 recipe. PV partition = r6 form
// (4 n-strips x 4 c-quarters). Accumulation order per output element
// unchanged -> bit-identical result.
__global__ __launch_bounds__(1024, 4) void final_kernel(
        const float* __restrict__ x, const unsigned short* __restrict__ qkT,
        const unsigned short* __restrict__ v, const unsigned short* __restrict__ wtb,
        const float* __restrict__ rowsuminv, const float* __restrict__ colsuminv,
        const float* __restrict__ bt, const float* __restrict__ gamma,
        const float* __restrict__ beta, const float* __restrict__ rmean,
        const float* __restrict__ rvar, float* __restrict__ out) {
    __shared__ union {
        struct {
            unsigned short vt[3][256][64];                              // 96 KB
            unsigned short kt[3][64][64];                               // 24 KB
        } s;
        unsigned short dsm[64][268];                                    // 33.5 KB
    } u;
    __shared__ unsigned short p_sh[2][4][16][68];                       // 17 KB
    __shared__ float ci[N_];                                            // 16 KB
    const int gid = blockIdx.x;
    const int xcd = gid & 7;
    const int b = xcd >> 1;                       // batch -> XCD pair (L2 fit)
    const int n0 = ((((unsigned)gid >> 3) << 1) | (xcd & 1)) * 64;
    const int tid = threadIdx.x;
    const int wave = tid >> 6, lane = tid & 63;
    const int ws = wave & 3, g = wave >> 2;
    const int quad = lane >> 4, l15 = lane & 15;
    const unsigned short* qb = qkT + (size_t)b * N_ * C4_;
    const unsigned short* vbg = v + (size_t)b * C_ * N_;
    const int rowA = lane >> 3;                  // 0..7  (== row&7 of dest row)
    const int swc = ((lane & 7) ^ rowA) * 8;     // swizzled source col (shorts)
    const int w8 = wave * 8;
    const int r7 = l15 & 7;
    const int c0s = (quad * 8) ^ (r7 << 3);
    const int c1s = (32 + quad * 8) ^ (r7 << 3);
    const unsigned short* qrow = qb + (size_t)(n0 + ws * 16 + l15) * C4_;
    const bf16x8 q0 = *reinterpret_cast<const bf16x8*>(qrow + quad * 8);
    const bf16x8 q1 = *reinterpret_cast<const bf16x8*>(qrow + 32 + quad * 8);
    const float rli = rowsuminv[(size_t)b * N_ + n0 + ws * 16 + l15];
    {
        const float4 c4 = *reinterpret_cast<const float4*>(colsuminv + (size_t)b * N_ + tid * 4);
        *reinterpret_cast<float4*>(&ci[tid * 4]) = c4;
    }
    asm volatile("s_waitcnt vmcnt(0)" ::: "memory");  // only DMAs counted below
#define STAGE_VT(sidx, bufS)                                                            \
    do {                                                                                \
        g2l16(vbg + (size_t)(w8 + rowA) * N_ + (sidx) * 64 + swc,                       \
              &u.s.vt[bufS][w8][0]);                                                    \
        g2l16(vbg + (size_t)(w8 + 128 + rowA) * N_ + (sidx) * 64 + swc,                 \
              &u.s.vt[bufS][w8 + 128][0]);                                              \
    } while (0)
#define STAGE_KT(sidx, bufS)                                                            \
    do {                                                                                \
        if (wave < 8)                                                                   \
            g2l16(qb + (size_t)((sidx) * 64 + w8 + rowA) * C4_ + swc,                   \
                  &u.s.kt[bufS][w8][0]);                                                \
    } while (0)
    // prologue: vt(0), kt(0), kt(1); full drain once (negligible), barrier.
    STAGE_VT(0, 0);
    STAGE_KT(0, 0);
    STAGE_KT(1, 1);
    asm volatile("s_waitcnt vmcnt(0)" ::: "memory");
    asm volatile("s_waitcnt lgkmcnt(0)" ::: "memory");
    __builtin_amdgcn_s_barrier();
    f32x4 acc[4];
#pragma unroll
    for (int j = 0; j < 4; ++j) acc[j] = (f32x4){0.f, 0.f, 0.f, 0.f};
    int bR = 0;      // = t mod 3
#pragma unroll 1
    for (int t = 0; t < 64; ++t) {
        // stage vt(t+1) (dist 1) and kt(t+2) (dist 2); targets were last read
        // >=1 barrier ago, and their reads were lgkm-drained before it.
        int bN = bR + 1; if (bN >= 3) bN -= 3;   // (t+1) mod 3
        int bN2 = bR + 2; if (bN2 >= 3) bN2 -= 3; // (t+2) mod 3
        if (t <= 62) STAGE_VT(t + 1, bN);
        if (t <= 61) STAGE_KT(t + 2, bN2);
        // energy(t): swapped mfma(K,Q); lane holds e[n=l15][m=t*64+g*16+quad*4+r]
        {
            const unsigned short(*ktb)[64] = u.s.kt[bR];
            const bf16x8 ka0 = *reinterpret_cast<const bf16x8*>(&ktb[g * 16 + l15][c0s]);
            const bf16x8 ka1 = *reinterpret_cast<const bf16x8*>(&ktb[g * 16 + l15][c1s]);
            f32x4 z = {0.f, 0.f, 0.f, 0.f};
            z = __builtin_amdgcn_mfma_f32_16x16x32_bf16(ka0, q0, z, 0, 0, 0);
            z = __builtin_amdgcn_mfma_f32_16x16x32_bf16(ka1, q1, z, 0, 0, 0);
            const float4 civ = *reinterpret_cast<const float4*>(&ci[t * 64 + g * 16 + quad * 4]);
            ushort4 pk;
            pk.x = bf16_rne(__expf(z[0]) * rli * civ.x);
            pk.y = bf16_rne(__expf(z[1]) * rli * civ.y);
            pk.z = bf16_rne(__expf(z[2]) * rli * civ.z);
            pk.w = bf16_rne(__expf(z[3]) * rli * civ.w);
            *reinterpret_cast<ushort4*>(&p_sh[t & 1][ws][l15][g * 16 + quad * 4]) = pk;
        }
        // PV(t-1): independent of energy(t) -- compiler interleaves them.
        if (t) {
            int bP = bR - 1; if (bP < 0) bP += 3;  // (t-1) mod 3
            const bf16x8 pa0 = *reinterpret_cast<const bf16x8*>(
                &p_sh[(t - 1) & 1][ws][l15][quad * 8]);
            const bf16x8 pa1 = *reinterpret_cast<const bf16x8*>(
                &p_sh[(t - 1) & 1][ws][l15][32 + quad * 8]);
            const unsigned short(*vtb)[64] = u.s.vt[bP];
            __builtin_amdgcn_s_setprio(1);
#pragma unroll
            for (int j = 0; j < 4; ++j) {
                const int vr = (g * 4 + j) * 16 + l15;
                const bf16x8 vb0 = *reinterpret_cast<const bf16x8*>(&vtb[vr][c0s]);
                const bf16x8 vb1 = *reinterpret_cast<const bf16x8*>(&vtb[vr][c1s]);
                acc[j] = __builtin_amdgcn_mfma_f32_16x16x32_bf16(pa0, vb0, acc[j], 0, 0, 0);
                acc[j] = __builtin_amdgcn_mfma_f32_16x16x32_bf16(pa1, vb1, acc[j], 0, 0, 0);
            }
            __builtin_amdgcn_s_setprio(0);
        }
        // drain own LDS ops (p write + all reads), counted vmcnt (never 0 in
        // steady state: vt(t+1)x2 + kt(t+2) stay in flight), ONE barrier.
        asm volatile("s_waitcnt lgkmcnt(0)" ::: "memory");
        if (t <= 61) {
            if (wave < 8) asm volatile("s_waitcnt vmcnt(3)" ::: "memory");
            else          asm volatile("s_waitcnt vmcnt(2)" ::: "memory");
        } else if (t == 62) {
            asm volatile("s_waitcnt vmcnt(2)" ::: "memory");
        } else {
            asm volatile("s_waitcnt vmcnt(0)" ::: "memory");
        }
        __builtin_amdgcn_s_barrier();
        ++bR; if (bR >= 3) bR = 0;
    }
    // tail: PV(63) -- p_sh[63&1=1], vt[63 mod 3 = 0]; no further staging.
    {
        const bf16x8 pa0 = *reinterpret_cast<const bf16x8*>(&p_sh[1][ws][l15][quad * 8]);
        const bf16x8 pa1 = *reinterpret_cast<const bf16x8*>(&p_sh[1][ws][l15][32 + quad * 8]);
        const unsigned short(*vtb)[64] = u.s.vt[0];
#pragma unroll
        for (int j = 0; j < 4; ++j) {
            const int vr = (g * 4 + j) * 16 + l15;
            const bf16x8 vb0 = *reinterpret_cast<const bf16x8*>(&vtb[vr][c0s]);
            const bf16x8 vb1 = *reinterpret_cast<const bf16x8*>(&vtb[vr][c1s]);
            acc[j] = __builtin_amdgcn_mfma_f32_16x16x32_bf16(pa0, vb0, acc[j], 0, 0, 0);
            acc[j] = __builtin_amdgcn_mfma_f32_16x16x32_bf16(pa1, vb1, acc[j], 0, 0, 0);
        }
    }
    __syncthreads();
    // dsm = x - x_r (bf16); acc[j][r] = x_r[n=ws*16+quad*4+r][c=(g*4+j)*16+l15]
#pragma unroll
    for (int j = 0; j < 4; ++j) {
        const int c = (g * 4 + j) * 16 + l15;
        const float4 xv = *reinterpret_cast<const float4*>(
            &x[((size_t)b * C_ + c) * N_ + n0 + ws * 16 + quad * 4]);
        const float xvr[4] = {xv.x, xv.y, xv.z, xv.w};
#pragma unroll
        for (int r = 0; r < 4; ++r)
            u.dsm[ws * 16 + quad * 4 + r][c] = bf16_rne(xvr[r] - acc[j][r]);
    }
    __syncthreads();
    // wt GEMM: 4 strips x 4 o-quarters
    bf16x8 da[8];
#pragma unroll
    for (int k = 0; k < 8; ++k)
        da[k] = *reinterpret_cast<const bf16x8*>(&u.dsm[ws * 16 + l15][k * 32 + quad * 8]);
    f32x4 tacc[4];
#pragma unroll
    for (int j = 0; j < 4; ++j) tacc[j] = (f32x4){0.f, 0.f, 0.f, 0.f};
#pragma unroll
    for (int j = 0; j < 4; ++j) {
        const int ot = g * 4 + j;
#pragma unroll
        for (int k = 0; k < 8; ++k) {
            const bf16x8 wb = *reinterpret_cast<const bf16x8*>(
                wtb + (size_t)(ot * 16 + l15) * C_ + k * 32 + quad * 8);
            tacc[j] = __builtin_amdgcn_mfma_f32_16x16x32_bf16(da[k], wb, tacc[j], 0, 0, 0);
        }
    }
#pragma unroll
    for (int j = 0; j < 4; ++j) {
        const int o = (g * 4 + j) * 16 + l15;
        const float gg = gamma[o] * rsqrtf(rvar[o] + 1e-5f);
        const float mn = rmean[o], bbet = beta[o], bo = bt[o];
        const size_t oi = ((size_t)b * C_ + o) * N_ + n0 + ws * 16 + quad * 4;
        const float4 xo = *reinterpret_cast<const float4*>(&x[oi]);
        float4 res;
        res.x = xo.x + fmaxf((tacc[j][0] + bo - mn) * gg + bbet, 0.f);
        res.y = xo.y + fmaxf((tacc[j][1] + bo - mn) * gg + bbet, 0.f);
        res.z = xo.z + fmaxf((tacc[j][2] + bo - mn) * gg + bbet, 0.f);
        res.w = xo.w + fmaxf((tacc[j][3] + bo - mn) * gg + bbet, 0.f);
        *reinterpret_cast<float4*>(&out[oi]) = res;
    }
#undef STAGE_VT
#undef STAGE_KT
}

}  // namespace

extern "C" void kernel_launch(void* const* d_in, const int* in_sizes, int n_in,
                              void* d_out, int out_size, void* d_ws, size_t ws_size,
                              hipStream_t stream) {
    const float* x = (const float*)d_in[0];
    const float* wq = (const float*)d_in[1];
    const float* wv = (const float*)d_in[2];
    const float* bv = (const float*)d_in[3];
    const float* wt = (const float*)d_in[4];
    const float* bt = (const float*)d_in[5];
    const float* gamma = (const float*)d_in[6];
    const float* beta = (const float*)d_in[7];
    const float* rmean = (const float*)d_in[8];
    const float* rvar = (const float*)d_in[9];
    float* out = (float*)d_out;

    char* base = (char*)d_ws;
    unsigned short* qkT = (unsigned short*)base;                        // 2 MB
    unsigned short* vw = (unsigned short*)(base + (2u << 20));          // 8 MB
    unsigned short* wtb = (unsigned short*)(base + (10u << 20));        // 128 KB
    unsigned short* wfrag = (unsigned short*)(base + (10u << 20) + (128u << 10));
    float* rowsuminv = (float*)(base + (10u << 20) + (288u << 10));     // 64 KB
    float* colsuminv = (float*)(base + (10u << 20) + (352u << 10));     // 64 KB

    cvt_kernel<<<dim3(144), dim3(256), 0, stream>>>(wq, wv, wt, wfrag, wtb);
    proj_kernel<<<dim3(N_ / 64, B_), dim3(1024), 0, stream>>>(x, wfrag, bv, qkT, vw);
    rowsum_kernel<<<dim3(N_ / 64 * B_), dim3(1024), 0, stream>>>(qkT, rowsuminv);
    colsum_kernel<<<dim3(N_ / 64 * B_), dim3(1024), 0, stream>>>(qkT, rowsuminv, colsuminv);
    final_kernel<<<dim3(N_ / 64 * B_), dim3(1024), 0, stream>>>(
        x, qkT, vw, wtb, rowsuminv, colsuminv, bt, gamma, beta, rmean, rvar, out);
}

// Round 9
// 223.028 us; speedup vs baseline: 2.5179x; 1.1059x over previous
//
#include <hip/hip_runtime.h>
#include <math.h>

namespace {

constexpr int B_ = 4;
constexpr int C_ = 256;
constexpr int C4_ = 64;
constexpr int N_ = 4096;

typedef __attribute__((ext_vector_type(8))) short bf16x8;
typedef __attribute__((ext_vector_type(4))) float f32x4;
typedef __attribute__((ext_vector_type(16))) float f32x16;

__device__ __forceinline__ unsigned short bf16_rne(float f) {
    unsigned u = __float_as_uint(f);
    u += 0x7fffu + ((u >> 16) & 1u);
    return (unsigned short)(u >> 16);
}

__device__ __forceinline__ float bf16_to_f(unsigned short s) {
    return __uint_as_float(((unsigned)s) << 16);
}

// Async global->LDS DMA, 16B per lane. LDS dest = wave-uniform base + lane*16.
__device__ __forceinline__ void g2l16(const unsigned short* g, unsigned short* l) {
    __builtin_amdgcn_global_load_lds(
        (const __attribute__((address_space(1))) unsigned int*)g,
        (__attribute__((address_space(3))) unsigned int*)l, 16, 0, 0);
}

// Convert wq||wv -> wfrag (per-lane MFMA B-fragment order), wt -> wtb.
__global__ __launch_bounds__(256) void cvt_kernel(
        const float* __restrict__ wq, const float* __restrict__ wv,
        const float* __restrict__ wt, unsigned short* __restrict__ wfrag,
        unsigned short* __restrict__ wtb) {
    const int i = (blockIdx.x * 256 + threadIdx.x) * 4;
    const float* src;
    unsigned short* dst;
    if (i < 81920) {
        src = (i < 16384) ? (wq + i) : (wv + (i - 16384));
        const int o = i >> 8, c = i & 255;
        const int gro = o >> 4, l15 = o & 15;
        const int ch = c >> 5, quad = (c >> 3) & 3, e = c & 7;
        dst = wfrag + (((gro * 8 + ch) * 64 + quad * 16 + l15) * 8 + e);
    } else {
        src = wt + (i - 81920);
        dst = wtb + (i - 81920);
    }
    const float4 f = *reinterpret_cast<const float4*>(src);
    ushort4 u;
    u.x = bf16_rne(f.x); u.y = bf16_rne(f.y);
    u.z = bf16_rne(f.z); u.w = bf16_rne(f.w);
    *reinterpret_cast<ushort4*>(dst) = u;
}

// MFMA projection (unchanged from round 7/8).
__global__ __launch_bounds__(1024, 4) void proj_kernel(
        const float* __restrict__ x, const unsigned short* __restrict__ wfragb,
        const float* __restrict__ bv, unsigned short* __restrict__ qkT,
        unsigned short* __restrict__ v) {
    __shared__ unsigned short xs[2][64][42];
    const int b = blockIdx.y;
    const int n0 = blockIdx.x * 64;
    const int tid = threadIdx.x;
    const int wave = tid >> 6, lane = tid & 63;
    const int ws = wave & 3, oq = wave >> 2;
    const int quad = lane >> 4, l15 = lane & 15;
    const int ca = tid >> 6, na = tid & 63;
    const int cb = (tid + 1024) >> 6, nb2 = (tid + 1024) & 63;
    f32x4 acc[5];
#pragma unroll
    for (int ot = 0; ot < 5; ++ot) acc[ot] = (f32x4){0.f, 0.f, 0.f, 0.f};
    xs[0][na][ca] = bf16_rne(x[((size_t)b * C_ + ca) * N_ + n0 + na]);
    xs[0][nb2][cb] = bf16_rne(x[((size_t)b * C_ + cb) * N_ + n0 + nb2]);
    __syncthreads();
    for (int ch = 0; ch < 8; ++ch) {
        const int buf = ch & 1;
        float la = 0.f, lb = 0.f;
        if (ch < 7) {
            la = x[((size_t)b * C_ + (ch + 1) * 32 + ca) * N_ + n0 + na];
            lb = x[((size_t)b * C_ + (ch + 1) * 32 + cb) * N_ + n0 + nb2];
        }
        const bf16x8 a = *reinterpret_cast<const bf16x8*>(&xs[buf][ws * 16 + l15][quad * 8]);
#pragma unroll
        for (int ot = 0; ot < 5; ++ot) {
            const int gro = oq * 5 + ot;
            const bf16x8 wb = *reinterpret_cast<const bf16x8*>(
                wfragb + (size_t)(((gro * 8 + ch) * 64 + lane) * 8));
            acc[ot] = __builtin_amdgcn_mfma_f32_16x16x32_bf16(a, wb, acc[ot], 0, 0, 0);
        }
        if (ch < 7) {
            xs[buf ^ 1][na][ca] = bf16_rne(la);
            xs[buf ^ 1][nb2][cb] = bf16_rne(lb);
        }
        __syncthreads();
    }
    const int n = n0 + ws * 16 + quad * 4;
#pragma unroll
    for (int ot = 0; ot < 5; ++ot) {
        const int gro = oq * 5 + ot;
        if (gro < 4) {
            const int o = gro * 16 + l15;
#pragma unroll
            for (int r = 0; r < 4; ++r)
                qkT[((size_t)b * N_ + n + r) * C4_ + o] = bf16_rne(acc[ot][r]);
        } else {
            const int c = (gro - 4) * 16 + l15;
            const float bb = bv[c];
            ushort4 u;
            u.x = bf16_rne(acc[ot][0] + bb);
            u.y = bf16_rne(acc[ot][1] + bb);
            u.z = bf16_rne(acc[ot][2] + bb);
            u.w = bf16_rne(acc[ot][3] + bb);
            *reinterpret_cast<ushort4*>(&v[((size_t)b * C_ + c) * N_ + n]) = u;
        }
    }
}

// rowsuminv (unchanged from round 6/7/8).
__global__ __launch_bounds__(1024, 4) void rowsum_kernel(
        const unsigned short* __restrict__ qkT, float* __restrict__ rowsuminv) {
    __shared__ unsigned short kt[3][256][64];
    __shared__ float red[2][8][2][16];
    const int gid = blockIdx.x;
    const int xcd = gid & 7;
    const int b = xcd >> 1;
    const int n0 = ((((unsigned)gid >> 3) << 1) | (xcd & 1)) * 64;
    const int tid = threadIdx.x;
    const int wave = tid >> 6, lane = tid & 63;
    const int nt = wave >> 3, ms = wave & 7;
    const int l31 = lane & 31, h = lane >> 5;
    const unsigned short* qb = qkT + (size_t)b * N_ * C4_;
    const int rowA = lane >> 3;
    const int swc = ((lane & 7) ^ rowA) * 8;
    const int w16 = wave * 16;
    const int r7 = l31 & 7;
    const unsigned short* qrow = qb + (size_t)(n0 + nt * 32 + l31) * C4_ + h * 8;
    bf16x8 qa[4];
#pragma unroll
    for (int j = 0; j < 4; ++j)
        qa[j] = *reinterpret_cast<const bf16x8*>(qrow + j * 16);
    asm volatile("s_waitcnt vmcnt(0)" ::: "memory");
#define RS_STAGE(sidx, bufS)                                                  \
    do {                                                                      \
        g2l16(qb + (size_t)((sidx) * 256 + w16 + rowA) * C4_ + swc,           \
              &kt[bufS][w16][0]);                                             \
        g2l16(qb + (size_t)((sidx) * 256 + w16 + 8 + rowA) * C4_ + swc,       \
              &kt[bufS][w16 + 8][0]);                                         \
    } while (0)
    RS_STAGE(0, 0);
    RS_STAGE(1, 1);
    asm volatile("s_waitcnt vmcnt(2)" ::: "memory");
    __builtin_amdgcn_s_barrier();
    f32x16 acc = (f32x16){0.f, 0.f, 0.f, 0.f, 0.f, 0.f, 0.f, 0.f,
                          0.f, 0.f, 0.f, 0.f, 0.f, 0.f, 0.f, 0.f};
    int bufR = 0;
#pragma unroll 1
    for (int t = 0; t < 16; ++t) {
        if (t <= 13) {
            int bufS = bufR + 2; if (bufS >= 3) bufS -= 3;
            RS_STAGE(t + 2, bufS);
        }
        f32x16 z = (f32x16){0.f, 0.f, 0.f, 0.f, 0.f, 0.f, 0.f, 0.f,
                            0.f, 0.f, 0.f, 0.f, 0.f, 0.f, 0.f, 0.f};
        __builtin_amdgcn_s_setprio(1);
#pragma unroll
        for (int j = 0; j < 4; ++j) {
            const bf16x8 kb = *reinterpret_cast<const bf16x8*>(
                &kt[bufR][ms * 32 + l31][(j * 16 + h * 8) ^ (r7 << 3)]);
            z = __builtin_amdgcn_mfma_f32_32x32x16_bf16(qa[j], kb, z, 0, 0, 0);
        }
        __builtin_amdgcn_s_setprio(0);
#pragma unroll
        for (int r = 0; r < 16; ++r) acc[r] += __expf(z[r]);
        asm volatile("s_waitcnt lgkmcnt(0)" ::: "memory");
        if (t <= 13)      asm volatile("s_waitcnt vmcnt(2)" ::: "memory");
        else if (t == 14) asm volatile("s_waitcnt vmcnt(0)" ::: "memory");
        __builtin_amdgcn_s_barrier();
        ++bufR; if (bufR >= 3) bufR = 0;
    }
#undef RS_STAGE
#pragma unroll
    for (int r = 0; r < 16; ++r) {
        float s = acc[r];
#pragma unroll
        for (int k = 1; k <= 16; k <<= 1) s += __shfl_xor(s, k, 64);
        if (l31 == 0) red[nt][ms][h][r] = s;
    }
    __syncthreads();
    if (tid < 64) {
        const int v = tid & 31, nt2 = tid >> 5;
        const int reg = (v & 3) | ((v >> 3) << 2);
        const int hh = (v >> 2) & 1;
        float sum = 0.f;
#pragma unroll
        for (int m = 0; m < 8; ++m) sum += red[nt2][m][hh][reg];
        rowsuminv[(size_t)b * N_ + n0 + nt2 * 32 + v] = 1.0f / sum;
    }
}

// colsum + (optional) p~ materialization: p~[b][n][m] = exp(e[n,m])*rowsuminv[n]
// (bf16). The 32x32 D-tile is transposed through a wave-private LDS tile and
// written out coalesced (32B/lane). Stores are accounted in the counted vmcnt
// (steady wait 4 = 2 DMA + 2 stores in flight).
template <int WP>
__global__ __launch_bounds__(1024, 4) void colsum_kernel(
        const unsigned short* __restrict__ qkT, const float* __restrict__ rowsuminv,
        float* __restrict__ colsuminv, unsigned short* __restrict__ ptg) {
    __shared__ float rl[N_];                     // 16 KB
    __shared__ unsigned short qt[3][256][64];    // 96 KB triple buffer (DMA)
    __shared__ unsigned short ptile[16][32][40]; // 40 KB wave-private transpose
    __shared__ float red2[8][2][32];             // 2 KB
    const int gid = blockIdx.x;
    const int xcd = gid & 7;
    const int b = xcd >> 1;
    const int m0 = ((((unsigned)gid >> 3) << 1) | (xcd & 1)) * 64;
    const int tid = threadIdx.x;
    const int wave = tid >> 6, lane = tid & 63;
    const int ms2 = wave >> 3, ns = wave & 7;
    const int l31 = lane & 31, h = lane >> 5;
    const unsigned short* qb = qkT + (size_t)b * N_ * C4_;
    const int rowA = lane >> 3;
    const int swc = ((lane & 7) ^ rowA) * 8;
    const int w16 = wave * 16;
    const int r7 = l31 & 7;
    for (int i = tid; i < N_; i += 1024) rl[i] = rowsuminv[(size_t)b * N_ + i];
    const unsigned short* krow = qb + (size_t)(m0 + ms2 * 32 + l31) * C4_ + h * 8;
    bf16x8 kbf[4];
#pragma unroll
    for (int j = 0; j < 4; ++j)
        kbf[j] = *reinterpret_cast<const bf16x8*>(krow + j * 16);
    asm volatile("s_waitcnt vmcnt(0)" ::: "memory");
#define CS_STAGE(sidx, bufS)                                                  \
    do {                                                                      \
        g2l16(qb + (size_t)((sidx) * 256 + w16 + rowA) * C4_ + swc,           \
              &qt[bufS][w16][0]);                                             \
        g2l16(qb + (size_t)((sidx) * 256 + w16 + 8 + rowA) * C4_ + swc,       \
              &qt[bufS][w16 + 8][0]);                                         \
    } while (0)
    CS_STAGE(0, 0);
    CS_STAGE(1, 1);
    asm volatile("s_waitcnt vmcnt(2)" ::: "memory");
    asm volatile("s_waitcnt lgkmcnt(0)" ::: "memory");
    __builtin_amdgcn_s_barrier();
    float csa = 0.f;
    int bufR = 0;
#pragma unroll 1
    for (int t = 0; t < 16; ++t) {
        if (t <= 13) {
            int bufS = bufR + 2; if (bufS >= 3) bufS -= 3;
            CS_STAGE(t + 2, bufS);
        }
        f32x16 z = (f32x16){0.f, 0.f, 0.f, 0.f, 0.f, 0.f, 0.f, 0.f,
                            0.f, 0.f, 0.f, 0.f, 0.f, 0.f, 0.f, 0.f};
        __builtin_amdgcn_s_setprio(1);
#pragma unroll
        for (int j = 0; j < 4; ++j) {
            const bf16x8 qa = *reinterpret_cast<const bf16x8*>(
                &qt[bufR][ns * 32 + l31][(j * 16 + h * 8) ^ (r7 << 3)]);
            z = __builtin_amdgcn_mfma_f32_32x32x16_bf16(qa, kbf[j], z, 0, 0, 0);
        }
        __builtin_amdgcn_s_setprio(0);
        const int nb = t * 256 + ns * 32 + 4 * h;
#pragma unroll
        for (int r = 0; r < 16; ++r) {
            const float ex = __expf(z[r]) * rl[nb + (r & 3) + 8 * (r >> 2)];
            csa += ex;
            if constexpr (WP)
                ptile[wave][(r & 3) + 8 * (r >> 2) + 4 * h][l31] = bf16_rne(ex);
        }
        if constexpr (WP) {
            // transpose write-out: lane -> (row r2, m-half hf); 32B per lane
            asm volatile("s_waitcnt lgkmcnt(0)" ::: "memory");
            const int r2 = lane >> 1, hf = lane & 1;
            const bf16x8 pr0 = *reinterpret_cast<const bf16x8*>(&ptile[wave][r2][hf * 16]);
            const bf16x8 pr1 = *reinterpret_cast<const bf16x8*>(&ptile[wave][r2][hf * 16 + 8]);
            unsigned short* pd = ptg + ((size_t)b * N_ + t * 256 + ns * 32 + r2) * N_
                                 + m0 + ms2 * 32 + hf * 16;
            *reinterpret_cast<bf16x8*>(pd) = pr0;
            *reinterpret_cast<bf16x8*>(pd + 8) = pr1;
        }
        asm volatile("s_waitcnt lgkmcnt(0)" ::: "memory");
        if constexpr (WP) {
            if (t <= 13)      asm volatile("s_waitcnt vmcnt(4)" ::: "memory");
            else if (t == 14) asm volatile("s_waitcnt vmcnt(2)" ::: "memory");
        } else {
            if (t <= 13)      asm volatile("s_waitcnt vmcnt(2)" ::: "memory");
            else if (t == 14) asm volatile("s_waitcnt vmcnt(0)" ::: "memory");
        }
        __builtin_amdgcn_s_barrier();
        ++bufR; if (bufR >= 3) bufR = 0;
    }
#undef CS_STAGE
    csa += __shfl_xor(csa, 32, 64);
    if (h == 0) red2[ns][ms2][l31] = csa;
    __syncthreads();
    if (tid < 64) {
        const int ml = tid & 31, mg = tid >> 5;
        float sum = 0.f;
#pragma unroll
        for (int n = 0; n < 8; ++n) sum += red2[n][mg][ml];
        colsuminv[(size_t)b * N_ + m0 + mg * 32 + ml] = 1.0f / (1e-9f + sum);
    }
}

// v~[b][c][m] = v[b][c][m] * colsuminv[b][m]  (in place, bf16).
__global__ __launch_bounds__(256) void scale_v_kernel(
        unsigned short* __restrict__ v, const float* __restrict__ colsuminv) {
    const size_t i8 = ((size_t)blockIdx.x * 256 + threadIdx.x) * 8;
    const int b = (int)(i8 >> 20);
    const int m = (int)(i8 & 4095);
    const float* cv = colsuminv + ((size_t)b << 12) + m;
    const float4 c0 = *reinterpret_cast<const float4*>(cv);
    const float4 c1 = *reinterpret_cast<const float4*>(cv + 4);
    const ushort4 a = *reinterpret_cast<const ushort4*>(v + i8);
    const ushort4 bb = *reinterpret_cast<const ushort4*>(v + i8 + 4);
    ushort4 oa, ob;
    oa.x = bf16_rne(bf16_to_f(a.x) * c0.x); oa.y = bf16_rne(bf16_to_f(a.y) * c0.y);
    oa.z = bf16_rne(bf16_to_f(a.z) * c0.z); oa.w = bf16_rne(bf16_to_f(a.w) * c0.w);
    ob.x = bf16_rne(bf16_to_f(bb.x) * c1.x); ob.y = bf16_rne(bf16_to_f(bb.y) * c1.y);
    ob.z = bf16_rne(bf16_to_f(bb.z) * c1.z); ob.w = bf16_rne(bf16_to_f(bb.w) * c1.w);
    *reinterpret_cast<ushort4*>(v + i8) = oa;
    *reinterpret_cast<ushort4*>(v + i8 + 4) = ob;
}

// Final v7 (pure GEMM): x_r = p~ . v~^T. DMA-staged p~-tile (same geometry as
// the old kt tile) + v~-tile, triple-buffered, counted vmcnt, 1 barrier/iter,
// NO energy phase / exp / p_sh. Epilogue (dsm -> wt GEMM -> BN) unchanged.
__global__ __launch_bounds__(1024, 4) void final7_kernel(
        const float* __restrict__ x, const unsigned short* __restrict__ ptg,
        const unsigned short* __restrict__ v, const unsigned short* __restrict__ wtb,
        const float* __restrict__ bt, const float* __restrict__ gamma,
        const float* __restrict__ beta, const float* __restrict__ rmean,
        const float* __restrict__ rvar, float* __restrict__ out) {
    __shared__ union {
        struct {
            unsigned short vt[3][256][64];                              // 96 KB
            unsigned short pt[3][64][64];                               // 24 KB
        } s;
        unsigned short dsm[64][268];                                    // 33.5 KB
    } u;
    const int gid = blockIdx.x;
    const int xcd = gid & 7;
    const int b = xcd >> 1;
    const int n0 = ((((unsigned)gid >> 3) << 1) | (xcd & 1)) * 64;
    const int tid = threadIdx.x;
    const int wave = tid >> 6, lane = tid & 63;
    const int ws = wave & 3, g = wave >> 2;
    const int quad = lane >> 4, l15 = lane & 15;
    const unsigned short* pb = ptg + ((size_t)b * N_ + n0) * N_;
    const unsigned short* vbg = v + (size_t)b * C_ * N_;
    const int rowA = lane >> 3;
    const int swc = ((lane & 7) ^ rowA) * 8;
    const int w8 = wave * 8;
    const int r7 = l15 & 7;
    const int c0s = (quad * 8) ^ (r7 << 3);
    const int c1s = (32 + quad * 8) ^ (r7 << 3);
    asm volatile("s_waitcnt vmcnt(0)" ::: "memory");  // only DMAs counted below
#define STAGE7(sidx, bufS)                                                              \
    do {                                                                                \
        g2l16(vbg + (size_t)(w8 + rowA) * N_ + (sidx) * 64 + swc,                       \
              &u.s.vt[bufS][w8][0]);                                                    \
        g2l16(vbg + (size_t)(w8 + 128 + rowA) * N_ + (sidx) * 64 + swc,                 \
              &u.s.vt[bufS][w8 + 128][0]);                                              \
        if (wave < 8)                                                                   \
            g2l16(pb + (size_t)(w8 + rowA) * N_ + (sidx) * 64 + swc,                    \
                  &u.s.pt[bufS][w8][0]);                                                \
    } while (0)
    STAGE7(0, 0);
    STAGE7(1, 1);
    if (wave < 8) asm volatile("s_waitcnt vmcnt(3)" ::: "memory");
    else          asm volatile("s_waitcnt vmcnt(2)" ::: "memory");
    __builtin_amdgcn_s_barrier();
    f32x4 acc[4];
#pragma unroll
    for (int j = 0; j < 4; ++j) acc[j] = (f32x4){0.f, 0.f, 0.f, 0.f};
    int bR = 0;
#pragma unroll 1
    for (int t = 0; t < 64; ++t) {
        if (t <= 61) {
            int bN2 = bR + 2; if (bN2 >= 3) bN2 -= 3;
            STAGE7(t + 2, bN2);
        }
        {
            const bf16x8 pa0 = *reinterpret_cast<const bf16x8*>(
                &u.s.pt[bR][ws * 16 + l15][c0s]);
            const bf16x8 pa1 = *reinterpret_cast<const bf16x8*>(
                &u.s.pt[bR][ws * 16 + l15][c1s]);
            const unsigned short(*vtb)[64] = u.s.vt[bR];
            __builtin_amdgcn_s_setprio(1);
#pragma unroll
            for (int j = 0; j < 4; ++j) {
                const int vr = (g * 4 + j) * 16 + l15;
                const bf16x8 vb0 = *reinterpret_cast<const bf16x8*>(&vtb[vr][c0s]);
                const bf16x8 vb1 = *reinterpret_cast<const bf16x8*>(&vtb[vr][c1s]);
                acc[j] = __builtin_amdgcn_mfma_f32_16x16x32_bf16(pa0, vb0, acc[j], 0, 0, 0);
                acc[j] = __builtin_amdgcn_mfma_f32_16x16x32_bf16(pa1, vb1, acc[j], 0, 0, 0);
            }
            __builtin_amdgcn_s_setprio(0);
        }
        asm volatile("s_waitcnt lgkmcnt(0)" ::: "memory");
        if (t <= 61) {
            if (wave < 8) asm volatile("s_waitcnt vmcnt(3)" ::: "memory");
            else          asm volatile("s_waitcnt vmcnt(2)" ::: "memory");
        } else if (t == 62) {
            asm volatile("s_waitcnt vmcnt(0)" ::: "memory");
        }
        __builtin_amdgcn_s_barrier();
        ++bR; if (bR >= 3) bR = 0;
    }
#undef STAGE7
    // dsm = x - x_r (bf16); acc[j][r] = x_r[n=ws*16+quad*4+r][c=(g*4+j)*16+l15]
#pragma unroll
    for (int j = 0; j < 4; ++j) {
        const int c = (g * 4 + j) * 16 + l15;
        const float4 xv = *reinterpret_cast<const float4*>(
            &x[((size_t)b * C_ + c) * N_ + n0 + ws * 16 + quad * 4]);
        const float xvr[4] = {xv.x, xv.y, xv.z, xv.w};
#pragma unroll
        for (int r = 0; r < 4; ++r)
            u.dsm[ws * 16 + quad * 4 + r][c] = bf16_rne(xvr[r] - acc[j][r]);
    }
    __syncthreads();
    bf16x8 da[8];
#pragma unroll
    for (int k = 0; k < 8; ++k)
        da[k] = *reinterpret_cast<const bf16x8*>(&u.dsm[ws * 16 + l15][k * 32 + quad * 8]);
    f32x4 tacc[4];
#pragma unroll
    for (int j = 0; j < 4; ++j) tacc[j] = (f32x4){0.f, 0.f, 0.f, 0.f};
#pragma unroll
    for (int j = 0; j < 4; ++j) {
        const int ot = g * 4 + j;
#pragma unroll
        for (int k = 0; k < 8; ++k) {
            const bf16x8 wb = *reinterpret_cast<const bf16x8*>(
                wtb + (size_t)(ot * 16 + l15) * C_ + k * 32 + quad * 8);
            tacc[j] = __builtin_amdgcn_mfma_f32_16x16x32_bf16(da[k], wb, tacc[j], 0, 0, 0);
        }
    }
#pragma unroll
    for (int j = 0; j < 4; ++j) {
        const int o = (g * 4 + j) * 16 + l15;
        const float gg = gamma[o] * rsqrtf(rvar[o] + 1e-5f);
        const float mn = rmean[o], bbet = beta[o], bo = bt[o];
        const size_t oi = ((size_t)b * C_ + o) * N_ + n0 + ws * 16 + quad * 4;
        const float4 xo = *reinterpret_cast<const float4*>(&x[oi]);
        float4 res;
        res.x = xo.x + fmaxf((tacc[j][0] + bo - mn) * gg + bbet, 0.f);
        res.y = xo.y + fmaxf((tacc[j][1] + bo - mn) * gg + bbet, 0.f);
        res.z = xo.z + fmaxf((tacc[j][2] + bo - mn) * gg + bbet, 0.f);
        res.w = xo.w + fmaxf((tacc[j][3] + bo - mn) * gg + bbet, 0.f);
        *reinterpret_cast<float4*>(&out[oi]) = res;
    }
}

// Final v6 (fallback when workspace < 144 MB): fused-phase pipeline, verified.
__global__ __launch_bounds__(1024, 4) void final_kernel(
        const float* __restrict__ x, const unsigned short* __restrict__ qkT,
        const unsigned short* __restrict__ v, const unsigned short* __restrict__ wtb,
        const float* __restrict__ rowsuminv, const float* __restrict__ colsuminv,
        const float* __restrict__ bt, const float* __restrict__ gamma,
        const float* __restrict__ beta, const float* __restrict__ rmean,
        const float* __restrict__ rvar, float* __restrict__ out) {
    __shared__ union {
        struct {
            unsigned short vt[3][256][64];
            unsigned short kt[3][64][64];
        } s;
        unsigned short dsm[64][268];
    } u;
    __shared__ unsigned short p_sh[2][4][16][68];
    __shared__ float ci[N_];
    const int gid = blockIdx.x;
    const int xcd = gid & 7;
    const int b = xcd >> 1;
    const int n0 = ((((unsigned)gid >> 3) << 1) | (xcd & 1)) * 64;
    const int tid = threadIdx.x;
    const int wave = tid >> 6, lane = tid & 63;
    const int ws = wave & 3, g = wave >> 2;
    const int quad = lane >> 4, l15 = lane & 15;
    const unsigned short* qb = qkT + (size_t)b * N_ * C4_;
    const unsigned short* vbg = v + (size_t)b * C_ * N_;
    const int rowA = lane >> 3;
    const int swc = ((lane & 7) ^ rowA) * 8;
    const int w8 = wave * 8;
    const int r7 = l15 & 7;
    const int c0s = (quad * 8) ^ (r7 << 3);
    const int c1s = (32 + quad * 8) ^ (r7 << 3);
    const unsigned short* qrow = qb + (size_t)(n0 + ws * 16 + l15) * C4_;
    const bf16x8 q0 = *reinterpret_cast<const bf16x8*>(qrow + quad * 8);
    const bf16x8 q1 = *reinterpret_cast<const bf16x8*>(qrow + 32 + quad * 8);
    const float rli = rowsuminv[(size_t)b * N_ + n0 + ws * 16 + l15];
    {
        const float4 c4 = *reinterpret_cast<const float4*>(colsuminv + (size_t)b * N_ + tid * 4);
        *reinterpret_cast<float4*>(&ci[tid * 4]) = c4;
    }
    asm volatile("s_waitcnt vmcnt(0)" ::: "memory");
#define STAGE_VT(sidx, bufS)                                                            \
    do {                                                                                \
        g2l16(vbg + (size_t)(w8 + rowA) * N_ + (sidx) * 64 + swc,                       \
              &u.s.vt[bufS][w8][0]);                                                    \
        g2l16(vbg + (size_t)(w8 + 128 + rowA) * N_ + (sidx) * 64 + swc,                 \
              &u.s.vt[bufS][w8 + 128][0]);                                              \
    } while (0)
#define STAGE_KT(sidx, bufS)                                                            \
    do {                                                                                \
        if (wave < 8)                                                                   \
            g2l16(qb + (size_t)((sidx) * 64 + w8 + rowA) * C4_ + swc,                   \
                  &u.s.kt[bufS][w8][0]);                                                \
    } while (0)
    STAGE_VT(0, 0);
    STAGE_KT(0, 0);
    STAGE_KT(1, 1);
    asm volatile("s_waitcnt vmcnt(0)" ::: "memory");
    asm volatile("s_waitcnt lgkmcnt(0)" ::: "memory");
    __builtin_amdgcn_s_barrier();
    f32x4 acc[4];
#pragma unroll
    for (int j = 0; j < 4; ++j) acc[j] = (f32x4){0.f, 0.f, 0.f, 0.f};
    int bR = 0;
#pragma unroll 1
    for (int t = 0; t < 64; ++t) {
        int bN = bR + 1; if (bN >= 3) bN -= 3;
        int bN2 = bR + 2; if (bN2 >= 3) bN2 -= 3;
        if (t <= 62) STAGE_VT(t + 1, bN);
        if (t <= 61) STAGE_KT(t + 2, bN2);
        {
            const unsigned short(*ktb)[64] = u.s.kt[bR];
            const bf16x8 ka0 = *reinterpret_cast<const bf16x8*>(&ktb[g * 16 + l15][c0s]);
            const bf16x8 ka1 = *reinterpret_cast<const bf16x8*>(&ktb[g * 16 + l15][c1s]);
            f32x4 z = {0.f, 0.f, 0.f, 0.f};
            z = __builtin_amdgcn_mfma_f32_16x16x32_bf16(ka0, q0, z, 0, 0, 0);
            z = __builtin_amdgcn_mfma_f32_16x16x32_bf16(ka1, q1, z, 0, 0, 0);
            const float4 civ = *reinterpret_cast<const float4*>(&ci[t * 64 + g * 16 + quad * 4]);
            ushort4 pk;
            pk.x = bf16_rne(__expf(z[0]) * rli * civ.x);
            pk.y = bf16_rne(__expf(z[1]) * rli * civ.y);
            pk.z = bf16_rne(__expf(z[2]) * rli * civ.z);
            pk.w = bf16_rne(__expf(z[3]) * rli * civ.w);
            *reinterpret_cast<ushort4*>(&p_sh[t & 1][ws][l15][g * 16 + quad * 4]) = pk;
        }
        if (t) {
            int bP = bR - 1; if (bP < 0) bP += 3;
            const bf16x8 pa0 = *reinterpret_cast<const bf16x8*>(
                &p_sh[(t - 1) & 1][ws][l15][quad * 8]);
            const bf16x8 pa1 = *reinterpret_cast<const bf16x8*>(
                &p_sh[(t - 1) & 1][ws][l15][32 + quad * 8]);
            const unsigned short(*vtb)[64] = u.s.vt[bP];
            __builtin_amdgcn_s_setprio(1);
#pragma unroll
            for (int j = 0; j < 4; ++j) {
                const int vr = (g * 4 + j) * 16 + l15;
                const bf16x8 vb0 = *reinterpret_cast<const bf16x8*>(&vtb[vr][c0s]);
                const bf16x8 vb1 = *reinterpret_cast<const bf16x8*>(&vtb[vr][c1s]);
                acc[j] = __builtin_amdgcn_mfma_f32_16x16x32_bf16(pa0, vb0, acc[j], 0, 0, 0);
                acc[j] = __builtin_amdgcn_mfma_f32_16x16x32_bf16(pa1, vb1, acc[j], 0, 0, 0);
            }
            __builtin_amdgcn_s_setprio(0);
        }
        asm volatile("s_waitcnt lgkmcnt(0)" ::: "memory");
        if (t <= 61) {
            if (wave < 8) asm volatile("s_waitcnt vmcnt(3)" ::: "memory");
            else          asm volatile("s_waitcnt vmcnt(2)" ::: "memory");
        } else if (t == 62) {
            asm volatile("s_waitcnt vmcnt(2)" ::: "memory");
        } else {
            asm volatile("s_waitcnt vmcnt(0)" ::: "memory");
        }
        __builtin_amdgcn_s_barrier();
        ++bR; if (bR >= 3) bR = 0;
    }
    {
        const bf16x8 pa0 = *reinterpret_cast<const bf16x8*>(&p_sh[1][ws][l15][quad * 8]);
        const bf16x8 pa1 = *reinterpret_cast<const bf16x8*>(&p_sh[1][ws][l15][32 + quad * 8]);
        const unsigned short(*vtb)[64] = u.s.vt[0];
#pragma unroll
        for (int j = 0; j < 4; ++j) {
            const int vr = (g * 4 + j) * 16 + l15;
            const bf16x8 vb0 = *reinterpret_cast<const bf16x8*>(&vtb[vr][c0s]);
            const bf16x8 vb1 = *reinterpret_cast<const bf16x8*>(&vtb[vr][c1s]);
            acc[j] = __builtin_amdgcn_mfma_f32_16x16x32_bf16(pa0, vb0, acc[j], 0, 0, 0);
            acc[j] = __builtin_amdgcn_mfma_f32_16x16x32_bf16(pa1, vb1, acc[j], 0, 0, 0);
        }
    }
    __syncthreads();
#pragma unroll
    for (int j = 0; j < 4; ++j) {
        const int c = (g * 4 + j) * 16 + l15;
        const float4 xv = *reinterpret_cast<const float4*>(
            &x[((size_t)b * C_ + c) * N_ + n0 + ws * 16 + quad * 4]);
        const float xvr[4] = {xv.x, xv.y, xv.z, xv.w};
#pragma unroll
        for (int r = 0; r < 4; ++r)
            u.dsm[ws * 16 + quad * 4 + r][c] = bf16_rne(xvr[r] - acc[j][r]);
    }
    __syncthreads();
    bf16x8 da[8];
#pragma unroll
    for (int k = 0; k < 8; ++k)
        da[k] = *reinterpret_cast<const bf16x8*>(&u.dsm[ws * 16 + l15][k * 32 + quad * 8]);
    f32x4 tacc[4];
#pragma unroll
    for (int j = 0; j < 4; ++j) tacc[j] = (f32x4){0.f, 0.f, 0.f, 0.f};
#pragma unroll
    for (int j = 0; j < 4; ++j) {
        const int ot = g * 4 + j;
#pragma unroll
        for (int k = 0; k < 8; ++k) {
            const bf16x8 wb = *reinterpret_cast<const bf16x8*>(
                wtb + (size_t)(ot * 16 + l15) * C_ + k * 32 + quad * 8);
            tacc[j] = __builtin_amdgcn_mfma_f32_16x16x32_bf16(da[k], wb, tacc[j], 0, 0, 0);
        }
    }
#pragma unroll
    for (int j = 0; j < 4; ++j) {
        const int o = (g * 4 + j) * 16 + l15;
        const float gg = gamma[o] * rsqrtf(rvar[o] + 1e-5f);
        const float mn = rmean[o], bbet = beta[o], bo = bt[o];
        const size_t oi = ((size_t)b * C_ + o) * N_ + n0 + ws * 16 + quad * 4;
        const float4 xo = *reinterpret_cast<const float4*>(&x[oi]);
        float4 res;
        res.x = xo.x + fmaxf((tacc[j][0] + bo - mn) * gg + bbet, 0.f);
        res.y = xo.y + fmaxf((tacc[j][1] + bo - mn) * gg + bbet, 0.f);
        res.z = xo.z + fmaxf((tacc[j][2] + bo - mn) * gg + bbet, 0.f);
        res.w = xo.w + fmaxf((tacc[j][3] + bo - mn) * gg + bbet, 0.f);
        *reinterpret_cast<float4*>(&out[oi]) = res;
    }
#undef STAGE_VT
#undef STAGE_KT
}

}  // namespace

extern "C" void kernel_launch(void* const* d_in, const int* in_sizes, int n_in,
                              void* d_out, int out_size, void* d_ws, size_t ws_size,
                              hipStream_t stream) {
    const float* x = (const float*)d_in[0];
    const float* wq = (const float*)d_in[1];
    const float* wv = (const float*)d_in[2];
    const float* bv = (const float*)d_in[3];
    const float* wt = (const float*)d_in[4];
    const float* bt = (const float*)d_in[5];
    const float* gamma = (const float*)d_in[6];
    const float* beta = (const float*)d_in[7];
    const float* rmean = (const float*)d_in[8];
    const float* rvar = (const float*)d_in[9];
    float* out = (float*)d_out;

    char* base = (char*)d_ws;
    unsigned short* qkT = (unsigned short*)base;                        // 2 MB
    unsigned short* vw = (unsigned short*)(base + (2u << 20));          // 8 MB
    unsigned short* wtb = (unsigned short*)(base + (10u << 20));        // 128 KB
    unsigned short* wfrag = (unsigned short*)(base + (10u << 20) + (128u << 10));
    float* rowsuminv = (float*)(base + (10u << 20) + (288u << 10));     // 64 KB
    float* colsuminv = (float*)(base + (10u << 20) + (352u << 10));     // 64 KB
    unsigned short* ptg = (unsigned short*)(base + (16ull << 20));      // 128 MB
    const bool big = ws_size >= (144ull << 20);

    cvt_kernel<<<dim3(144), dim3(256), 0, stream>>>(wq, wv, wt, wfrag, wtb);
    proj_kernel<<<dim3(N_ / 64, B_), dim3(1024), 0, stream>>>(x, wfrag, bv, qkT, vw);
    rowsum_kernel<<<dim3(N_ / 64 * B_), dim3(1024), 0, stream>>>(qkT, rowsuminv);
    if (big) {
        colsum_kernel<1><<<dim3(N_ / 64 * B_), dim3(1024), 0, stream>>>(
            qkT, rowsuminv, colsuminv, ptg);
        scale_v_kernel<<<dim3(2048), dim3(256), 0, stream>>>(vw, colsuminv);
        final7_kernel<<<dim3(N_ / 64 * B_), dim3(1024), 0, stream>>>(
            x, ptg, vw, wtb, bt, gamma, beta, rmean, rvar, out);
    } else {
        colsum_kernel<0><<<dim3(N_ / 64 * B_), dim3(1024), 0, stream>>>(
            qkT, rowsuminv, colsuminv, nullptr);
        final_kernel<<<dim3(N_ / 64 * B_), dim3(1024), 0, stream>>>(
            x, qkT, vw, wtb, rowsuminv, colsuminv, bt, gamma, beta, rmean, rvar, out);
    }
}